// Round 1
// baseline (332.756 us; speedup 1.0000x reference)
//
#include <hip/hip_runtime.h>
#include <stdint.h>

// Problem constants (reference: B=2, L=2048, DIM=1024, 16 heads x 64)
#define BATCH 2
#define SEQ   2048
#define DIM   1024
#define NH    16
#define HD    64
#define MTOT  (BATCH*SEQ)   // 4096
#define QK_SCALE 0.125f     // 64^-0.5
#define LN_EPS 1e-5f

typedef __bf16 bf16x8 __attribute__((ext_vector_type(8)));
typedef float  f32x4  __attribute__((ext_vector_type(4)));

__device__ __forceinline__ unsigned short f2bf(float f) {
  uint32_t u = __float_as_uint(f);
  u += 0x7fffu + ((u >> 16) & 1u);      // RNE
  return (unsigned short)(u >> 16);
}

__device__ __forceinline__ void gload_lds16(const void* g, void* lds) {
  __builtin_amdgcn_global_load_lds(
      (const __attribute__((address_space(1))) uint32_t*)g,
      (__attribute__((address_space(3))) uint32_t*)lds, 16, 0, 0);
}

// ---------------- f32 -> bf16 conversion (inputs + weights) ----------------
__global__ void cvt_f32_bf16(const float* __restrict__ s0, unsigned short* __restrict__ d0,
                             const float* __restrict__ s1, unsigned short* __restrict__ d1,
                             const float* __restrict__ s2, unsigned short* __restrict__ d2,
                             const float* __restrict__ s3, unsigned short* __restrict__ d3,
                             int n) {
  int z = blockIdx.y;
  const float* s = z == 0 ? s0 : z == 1 ? s1 : z == 2 ? s2 : s3;
  unsigned short* d = z == 0 ? d0 : z == 1 ? d1 : z == 2 ? d2 : d3;
  if (s == nullptr) return;
  int i = (blockIdx.x * 256 + threadIdx.x) * 4;
  if (i >= n) return;
  float4 v = *(const float4*)(s + i);
  ushort4 o;
  o.x = f2bf(v.x); o.y = f2bf(v.y); o.z = f2bf(v.z); o.w = f2bf(v.w);
  *(ushort4*)(d + i) = o;
}

// ---------------- GEMM: C[4096][1024] = A[4096][1024] @ W[1024][1024]^T ----
// 128x128 tile, BK=32, 4 waves (2x2), each wave 64x64 (4x4 16x16x32 frags).
// LDS layout [kb(4)][row(128)][8] so frag ds_read_b128 lanes are 16B-strided.
// MODE 0: LN(gq,bq)*SCALE -> qh [B][H][L][64] bf16
// MODE 1: LN(gk,bk)       -> kh [B][H][L][64] bf16
// MODE 2: plain           -> vT [B][H][64][L] bf16   (transposed for PV B-frags)
// MODE 3: + bias          -> out f32 [4096][1024]
template<int MODE>
__global__ __launch_bounds__(256)
void gemm_bt(const unsigned short* __restrict__ A, const unsigned short* __restrict__ W,
             const float* __restrict__ gamma, const float* __restrict__ beta,
             unsigned short* __restrict__ outb, float* __restrict__ outf,
             const float* __restrict__ bias) {
  __shared__ unsigned short Asm[4096];   // [kb][row][8] : 8KB
  __shared__ unsigned short Bsm[4096];
  const int t = threadIdx.x;
  const int w = t >> 6, l = t & 63;
  const int l15 = l & 15, lhi = l >> 4;
  const int wm = w >> 1, wn = w & 1;
  const int m0 = blockIdx.x * 128, n0 = blockIdx.y * 128;

  f32x4 acc[4][4] = {};

  for (int kt = 0; kt < 32; ++kt) {
    const int k0 = kt * 32;
#pragma unroll
    for (int p = 0; p < 2; ++p) {
      int tp = p * 256 + t;
      int kb = tp >> 7, row = tp & 127;
      gload_lds16(A + (size_t)(m0 + row) * 1024 + k0 + kb * 8, &Asm[tp * 8]);
      gload_lds16(W + (size_t)(n0 + row) * 1024 + k0 + kb * 8, &Bsm[tp * 8]);
    }
    __syncthreads();   // drains vmcnt -> LDS tiles valid
    bf16x8 af[4], bfr[4];
#pragma unroll
    for (int mi = 0; mi < 4; ++mi)
      af[mi] = *(const bf16x8*)&Asm[lhi * 1024 + (wm * 64 + mi * 16 + l15) * 8];
#pragma unroll
    for (int ni = 0; ni < 4; ++ni)
      bfr[ni] = *(const bf16x8*)&Bsm[lhi * 1024 + (wn * 64 + ni * 16 + l15) * 8];
#pragma unroll
    for (int mi = 0; mi < 4; ++mi)
#pragma unroll
      for (int ni = 0; ni < 4; ++ni)
        acc[mi][ni] = __builtin_amdgcn_mfma_f32_16x16x32_bf16(af[mi], bfr[ni], acc[mi][ni], 0, 0, 0);
    __syncthreads();   // compute done before next stage overwrites LDS
  }

  // C(row,col): row = m0+wm*64+mi*16+lhi*4+r ; col = n0+wn*64+ni*16+l15
  if (MODE == 3) {
    float bb[4];
#pragma unroll
    for (int ni = 0; ni < 4; ++ni) bb[ni] = bias[n0 + wn * 64 + ni * 16 + l15];
#pragma unroll
    for (int mi = 0; mi < 4; ++mi)
#pragma unroll
      for (int r = 0; r < 4; ++r) {
        int gm = m0 + wm * 64 + mi * 16 + lhi * 4 + r;
        float* op = outf + (size_t)gm * 1024 + n0 + wn * 64 + l15;
#pragma unroll
        for (int ni = 0; ni < 4; ++ni) op[ni * 16] = acc[mi][ni][r] + bb[ni];
      }
  } else if (MODE == 2) {
    const int h = (n0 + wn * 64) >> 6;
#pragma unroll
    for (int mi = 0; mi < 4; ++mi)
#pragma unroll
      for (int r = 0; r < 4; ++r) {
        int gm = m0 + wm * 64 + mi * 16 + lhi * 4 + r;
        int b = gm >> 11, pos = gm & 2047;
#pragma unroll
        for (int ni = 0; ni < 4; ++ni) {
          int d = ni * 16 + l15;
          outb[(((size_t)(b * NH + h)) * 64 + d) * SEQ + pos] = f2bf(acc[mi][ni][r]);
        }
      }
  } else {
    const int h = (n0 + wn * 64) >> 6;
    float g[4], bt[4];
#pragma unroll
    for (int ni = 0; ni < 4; ++ni) { g[ni] = gamma[ni * 16 + l15]; bt[ni] = beta[ni * 16 + l15]; }
#pragma unroll
    for (int mi = 0; mi < 4; ++mi)
#pragma unroll
      for (int r = 0; r < 4; ++r) {
        float x[4], s = 0.f, s2 = 0.f;
#pragma unroll
        for (int ni = 0; ni < 4; ++ni) { x[ni] = acc[mi][ni][r]; s += x[ni]; s2 += x[ni] * x[ni]; }
#pragma unroll
        for (int msk = 1; msk < 16; msk <<= 1) {
          s  += __shfl_xor(s,  msk, 64);
          s2 += __shfl_xor(s2, msk, 64);
        }
        float mu = s * (1.f / 64.f);
        float var = s2 * (1.f / 64.f) - mu * mu;
        float rstd = rsqrtf(var + LN_EPS);
        int gm = m0 + wm * 64 + mi * 16 + lhi * 4 + r;
        int b = gm >> 11, pos = gm & 2047;
        size_t base = (((size_t)(b * NH + h)) * SEQ + pos) * 64;
#pragma unroll
        for (int ni = 0; ni < 4; ++ni) {
          float y = (x[ni] - mu) * rstd * g[ni] + bt[ni];
          if (MODE == 0) y *= QK_SCALE;
          outb[base + ni * 16 + l15] = f2bf(y);
        }
      }
  }
}

// ---------------- Sigmoid attention: O = sigmoid(Qh Kh^T) Vh ----------------
// grid (16 q-tiles, 32 bh). 4 waves, each owns 32 q rows. K/V frags straight
// from global (L2-resident). P transposed through per-wave padded LDS.
__global__ __launch_bounds__(256)
void attn_kernel(const unsigned short* __restrict__ qh,
                 const unsigned short* __restrict__ kh,
                 const unsigned short* __restrict__ vT,
                 unsigned short* __restrict__ x) {
  __shared__ unsigned short Plds[4 * 32 * 136];   // per-wave [32][136] (pad: 2-way only)
  const int t = threadIdx.x;
  const int w = t >> 6, l = t & 63;
  const int l15 = l & 15, lhi = l >> 4;
  const int qt = blockIdx.x, bh = blockIdx.y;
  const int b = bh >> 4, h = bh & 15;
  const unsigned short* Q = qh + (size_t)bh * SEQ * 64;
  const unsigned short* K = kh + (size_t)bh * SEQ * 64;
  const unsigned short* V = vT + (size_t)bh * 64 * SEQ;
  unsigned short* Pw = &Plds[w * 32 * 136];
  const int qbase = qt * 128 + w * 32;

  bf16x8 qf[2][2];
#pragma unroll
  for (int mi = 0; mi < 2; ++mi)
#pragma unroll
    for (int kb = 0; kb < 2; ++kb)
      qf[mi][kb] = *(const bf16x8*)&Q[(size_t)(qbase + mi * 16 + l15) * 64 + kb * 32 + lhi * 8];

  f32x4 o[2][4] = {};

  for (int kv = 0; kv < 16; ++kv) {
    const int kv0 = kv * 128;
    f32x4 s[2][8] = {};
#pragma unroll
    for (int ni = 0; ni < 8; ++ni) {
#pragma unroll
      for (int kb = 0; kb < 2; ++kb) {
        bf16x8 kf = *(const bf16x8*)&K[(size_t)(kv0 + ni * 16 + l15) * 64 + kb * 32 + lhi * 8];
        s[0][ni] = __builtin_amdgcn_mfma_f32_16x16x32_bf16(qf[0][kb], kf, s[0][ni], 0, 0, 0);
        s[1][ni] = __builtin_amdgcn_mfma_f32_16x16x32_bf16(qf[1][kb], kf, s[1][ni], 0, 0, 0);
      }
    }
    // sigmoid -> bf16 -> per-wave LDS (C-layout write, A-frag read)
#pragma unroll
    for (int mi = 0; mi < 2; ++mi)
#pragma unroll
      for (int ni = 0; ni < 8; ++ni)
#pragma unroll
        for (int r = 0; r < 4; ++r) {
          float sv = s[mi][ni][r];
          float p = 1.0f / (1.0f + __expf(-sv));
          Pw[(mi * 16 + lhi * 4 + r) * 136 + ni * 16 + l15] = f2bf(p);
        }
    // PV: O[32][64] += P[32][128] @ V[128][64]
#pragma unroll
    for (int kq = 0; kq < 4; ++kq) {
      bf16x8 pf0 = *(const bf16x8*)&Pw[(l15) * 136 + kq * 32 + lhi * 8];
      bf16x8 pf1 = *(const bf16x8*)&Pw[(16 + l15) * 136 + kq * 32 + lhi * 8];
#pragma unroll
      for (int di = 0; di < 4; ++di) {
        bf16x8 vf = *(const bf16x8*)&V[(size_t)(di * 16 + l15) * SEQ + kv0 + kq * 32 + lhi * 8];
        o[0][di] = __builtin_amdgcn_mfma_f32_16x16x32_bf16(pf0, vf, o[0][di], 0, 0, 0);
        o[1][di] = __builtin_amdgcn_mfma_f32_16x16x32_bf16(pf1, vf, o[1][di], 0, 0, 0);
      }
    }
  }
  // store x[b][pos][h*64+d] bf16
#pragma unroll
  for (int mi = 0; mi < 2; ++mi)
#pragma unroll
    for (int r = 0; r < 4; ++r) {
      int pos = qbase + mi * 16 + lhi * 4 + r;
      size_t base = ((size_t)b * SEQ + pos) * DIM + h * 64;
#pragma unroll
      for (int di = 0; di < 4; ++di)
        x[base + di * 16 + l15] = f2bf(o[mi][di][r]);
    }
}

// ---------------- launch ----------------
extern "C" void kernel_launch(void* const* d_in, const int* in_sizes, int n_in,
                              void* d_out, int out_size, void* d_ws, size_t ws_size,
                              hipStream_t stream) {
  (void)in_sizes; (void)n_in; (void)out_size; (void)ws_size;
  const float* q  = (const float*)d_in[0];
  const float* k  = (const float*)d_in[1];
  const float* v  = (const float*)d_in[2];
  const float* Wq = (const float*)d_in[3];
  const float* Wk = (const float*)d_in[4];
  const float* Wv = (const float*)d_in[5];
  const float* gq = (const float*)d_in[6];
  const float* bq = (const float*)d_in[7];
  const float* gk = (const float*)d_in[8];
  const float* bk = (const float*)d_in[9];
  const float* Wo = (const float*)d_in[10];
  const float* bo = (const float*)d_in[11];
  float* out = (float*)d_out;

  char* ws = (char*)d_ws;
  const size_t MB = 1ull << 20;
  unsigned short* qb  = (unsigned short*)(ws + 0);        // 8MB, reused as x after proj-q
  unsigned short* kb  = (unsigned short*)(ws + 8  * MB);
  unsigned short* vb  = (unsigned short*)(ws + 16 * MB);
  unsigned short* Wqb = (unsigned short*)(ws + 24 * MB);  // 2MB each
  unsigned short* Wkb = (unsigned short*)(ws + 26 * MB);
  unsigned short* Wvb = (unsigned short*)(ws + 28 * MB);
  unsigned short* Wob = (unsigned short*)(ws + 30 * MB);
  unsigned short* qhb = (unsigned short*)(ws + 32 * MB);  // [B][H][L][64]
  unsigned short* khb = (unsigned short*)(ws + 40 * MB);  // [B][H][L][64]
  unsigned short* vTb = (unsigned short*)(ws + 48 * MB);  // [B][H][64][L]
  unsigned short* xb  = qb;                               // [4096][1024] (qb dead by then)

  const int nIn = MTOT * DIM;      // 4,194,304
  const int nW  = DIM * DIM;       // 1,048,576

  cvt_f32_bf16<<<dim3(nIn / 1024, 3), 256, 0, stream>>>(q, qb, k, kb, v, vb, nullptr, nullptr, nIn);
  cvt_f32_bf16<<<dim3(nW / 1024, 4), 256, 0, stream>>>(Wq, Wqb, Wk, Wkb, Wv, Wvb, Wo, Wob, nW);

  dim3 gg(MTOT / 128, DIM / 128);  // 32 x 8
  gemm_bt<0><<<gg, 256, 0, stream>>>(qb, Wqb, gq, bq, qhb, nullptr, nullptr);
  gemm_bt<1><<<gg, 256, 0, stream>>>(kb, Wkb, gk, bk, khb, nullptr, nullptr);
  gemm_bt<2><<<gg, 256, 0, stream>>>(vb, Wvb, nullptr, nullptr, vTb, nullptr, nullptr);

  attn_kernel<<<dim3(SEQ / 128, BATCH * NH), 256, 0, stream>>>(qhb, khb, vTb, xb);

  gemm_bt<3><<<gg, 256, 0, stream>>>(xb, Wob, nullptr, nullptr, nullptr, out, bo);
}

// Round 2
// 186.950 us; speedup vs baseline: 1.7799x; 1.7799x over previous
//
#include <hip/hip_runtime.h>
#include <stdint.h>

// B=2, L=2048, DIM=1024, 16 heads x 64
#define BATCH 2
#define SEQ   2048
#define DIM   1024
#define NH    16
#define MTOT  (BATCH*SEQ)   // 4096
#define QK_SCALE 0.125f
#define LN_EPS 1e-5f

typedef __bf16 bf16x8 __attribute__((ext_vector_type(8)));
typedef float  f32x4  __attribute__((ext_vector_type(4)));

__device__ __forceinline__ unsigned short f2bf(float f) {
  uint32_t u = __float_as_uint(f);
  u += 0x7fffu + ((u >> 16) & 1u);      // RNE
  return (unsigned short)(u >> 16);
}
__device__ __forceinline__ unsigned short f2bf_rh(float f) {  // round-half-up (cheap, P>=0)
  uint32_t u = __float_as_uint(f) + 0x8000u;
  return (unsigned short)(u >> 16);
}

__device__ __forceinline__ void gload_lds16(const void* g, void* lds) {
  __builtin_amdgcn_global_load_lds(
      (const __attribute__((address_space(1))) uint32_t*)g,
      (__attribute__((address_space(3))) uint32_t*)lds, 16, 0, 0);
}

// ---------------- f32 -> bf16 conversion ----------------
__global__ void cvt_f32_bf16(const float* __restrict__ s0, unsigned short* __restrict__ d0,
                             const float* __restrict__ s1, unsigned short* __restrict__ d1,
                             const float* __restrict__ s2, unsigned short* __restrict__ d2,
                             const float* __restrict__ s3, unsigned short* __restrict__ d3,
                             int n) {
  int z = blockIdx.y;
  const float* s = z == 0 ? s0 : z == 1 ? s1 : z == 2 ? s2 : s3;
  unsigned short* d = z == 0 ? d0 : z == 1 ? d1 : z == 2 ? d2 : d3;
  if (s == nullptr) return;
  int i = (blockIdx.x * 256 + threadIdx.x) * 4;
  if (i >= n) return;
  float4 v = *(const float4*)(s + i);
  ushort4 o;
  o.x = f2bf(v.x); o.y = f2bf(v.y); o.z = f2bf(v.z); o.w = f2bf(v.w);
  *(ushort4*)(d + i) = o;
}

// ---------------- QKV projections, one launch ----------------
// C[4096][1024] = A @ W^T. BM=128, BN=64 (one head per y-block), BK=32.
// 4 waves stacked on M; wave tile 32x64 = acc[2][4]. grid (32,16,3).
// z=0: LN(gq,bq)*SCALE -> qh [BH][L][64] ; z=1: LN(gk,bk) -> kh ; z=2: vT [BH][64][L]
__global__ __launch_bounds__(256)
void gemm_qkv(const unsigned short* __restrict__ Aq, const unsigned short* __restrict__ Ak,
              const unsigned short* __restrict__ Av,
              const unsigned short* __restrict__ Wqp, const unsigned short* __restrict__ Wkp,
              const unsigned short* __restrict__ Wvp,
              const float* __restrict__ gq, const float* __restrict__ bq,
              const float* __restrict__ gk, const float* __restrict__ bk,
              unsigned short* __restrict__ qh, unsigned short* __restrict__ kh,
              unsigned short* __restrict__ vT) {
  __shared__ unsigned short Asm[4096];  // [kb4][128][8]
  __shared__ unsigned short Bsm[2048];  // [kb4][64][8]
  const int z = blockIdx.z;
  const unsigned short* A = z == 0 ? Aq : z == 1 ? Ak : Av;
  const unsigned short* W = z == 0 ? Wqp : z == 1 ? Wkp : Wvp;
  const int t = threadIdx.x, w = t >> 6, l = t & 63, l15 = l & 15, lhi = l >> 4;
  const int m0 = blockIdx.x * 128, n0 = blockIdx.y * 64;
  const int h = blockIdx.y;    // BN=64 -> head index

  f32x4 acc[2][4] = {};
  for (int kt = 0; kt < 32; ++kt) {
    const int k0 = kt * 32;
    gload_lds16(A + (size_t)(m0 + (t & 127)) * 1024 + k0 + (t >> 7) * 8, &Asm[t * 8]);
    {
      int tp = 256 + t;
      gload_lds16(A + (size_t)(m0 + (tp & 127)) * 1024 + k0 + (tp >> 7) * 8, &Asm[tp * 8]);
    }
    gload_lds16(W + (size_t)(n0 + (t & 63)) * 1024 + k0 + (t >> 6) * 8, &Bsm[t * 8]);
    __syncthreads();
    bf16x8 af[2], bfr[4];
#pragma unroll
    for (int mi = 0; mi < 2; ++mi)
      af[mi] = *(const bf16x8*)&Asm[lhi * 1024 + (w * 32 + mi * 16 + l15) * 8];
#pragma unroll
    for (int ni = 0; ni < 4; ++ni)
      bfr[ni] = *(const bf16x8*)&Bsm[lhi * 512 + (ni * 16 + l15) * 8];
    __builtin_amdgcn_s_setprio(1);
#pragma unroll
    for (int mi = 0; mi < 2; ++mi)
#pragma unroll
      for (int ni = 0; ni < 4; ++ni)
        acc[mi][ni] = __builtin_amdgcn_mfma_f32_16x16x32_bf16(af[mi], bfr[ni], acc[mi][ni], 0, 0, 0);
    __builtin_amdgcn_s_setprio(0);
    __syncthreads();
  }

  if (z == 2) {
#pragma unroll
    for (int mi = 0; mi < 2; ++mi)
#pragma unroll
      for (int r = 0; r < 4; ++r) {
        int gm = m0 + w * 32 + mi * 16 + lhi * 4 + r;
        int b = gm >> 11, pos = gm & 2047;
#pragma unroll
        for (int ni = 0; ni < 4; ++ni)
          vT[(((size_t)(b * NH + h)) * 64 + ni * 16 + l15) * SEQ + pos] = f2bf(acc[mi][ni][r]);
      }
  } else {
    const float* G  = z ? gk : gq;
    const float* Bt = z ? bk : bq;
    unsigned short* outp = z ? kh : qh;
    const float sc = z ? 1.f : QK_SCALE;
    float g[4], bt[4];
#pragma unroll
    for (int ni = 0; ni < 4; ++ni) { g[ni] = G[ni * 16 + l15]; bt[ni] = Bt[ni * 16 + l15]; }
#pragma unroll
    for (int mi = 0; mi < 2; ++mi)
#pragma unroll
      for (int r = 0; r < 4; ++r) {
        float x[4], s = 0.f, s2 = 0.f;
#pragma unroll
        for (int ni = 0; ni < 4; ++ni) { x[ni] = acc[mi][ni][r]; s += x[ni]; s2 += x[ni] * x[ni]; }
#pragma unroll
        for (int msk = 1; msk < 16; msk <<= 1) {
          s  += __shfl_xor(s,  msk, 64);
          s2 += __shfl_xor(s2, msk, 64);
        }
        float mu = s * (1.f / 64.f);
        float var = s2 * (1.f / 64.f) - mu * mu;
        float rstd = rsqrtf(var + LN_EPS);
        int gm = m0 + w * 32 + mi * 16 + lhi * 4 + r;
        int b = gm >> 11, pos = gm & 2047;
        size_t base = (((size_t)(b * NH + h)) * SEQ + pos) * 64;
#pragma unroll
        for (int ni = 0; ni < 4; ++ni) {
          float y = ((x[ni] - mu) * rstd * g[ni] + bt[ni]) * sc;
          outp[base + ni * 16 + l15] = f2bf(y);
        }
      }
  }
}

// ---------------- out projection: out = x @ Wo^T + bo (f32) ----------------
__global__ __launch_bounds__(256)
void gemm_out(const unsigned short* __restrict__ A, const unsigned short* __restrict__ W,
              const float* __restrict__ bias, float* __restrict__ outf) {
  __shared__ unsigned short Asm[4096];
  __shared__ unsigned short Bsm[2048];
  const int t = threadIdx.x, w = t >> 6, l = t & 63, l15 = l & 15, lhi = l >> 4;
  const int m0 = blockIdx.x * 128, n0 = blockIdx.y * 64;
  f32x4 acc[2][4] = {};
  for (int kt = 0; kt < 32; ++kt) {
    const int k0 = kt * 32;
    gload_lds16(A + (size_t)(m0 + (t & 127)) * 1024 + k0 + (t >> 7) * 8, &Asm[t * 8]);
    {
      int tp = 256 + t;
      gload_lds16(A + (size_t)(m0 + (tp & 127)) * 1024 + k0 + (tp >> 7) * 8, &Asm[tp * 8]);
    }
    gload_lds16(W + (size_t)(n0 + (t & 63)) * 1024 + k0 + (t >> 6) * 8, &Bsm[t * 8]);
    __syncthreads();
    bf16x8 af[2], bfr[4];
#pragma unroll
    for (int mi = 0; mi < 2; ++mi)
      af[mi] = *(const bf16x8*)&Asm[lhi * 1024 + (w * 32 + mi * 16 + l15) * 8];
#pragma unroll
    for (int ni = 0; ni < 4; ++ni)
      bfr[ni] = *(const bf16x8*)&Bsm[lhi * 512 + (ni * 16 + l15) * 8];
    __builtin_amdgcn_s_setprio(1);
#pragma unroll
    for (int mi = 0; mi < 2; ++mi)
#pragma unroll
      for (int ni = 0; ni < 4; ++ni)
        acc[mi][ni] = __builtin_amdgcn_mfma_f32_16x16x32_bf16(af[mi], bfr[ni], acc[mi][ni], 0, 0, 0);
    __builtin_amdgcn_s_setprio(0);
    __syncthreads();
  }
  float bb[4];
#pragma unroll
  for (int ni = 0; ni < 4; ++ni) bb[ni] = bias[n0 + ni * 16 + l15];
#pragma unroll
  for (int mi = 0; mi < 2; ++mi)
#pragma unroll
    for (int r = 0; r < 4; ++r) {
      int gm = m0 + w * 32 + mi * 16 + lhi * 4 + r;
      float* op = outf + (size_t)gm * 1024 + n0 + l15;
#pragma unroll
      for (int ni = 0; ni < 4; ++ni) op[ni * 16] = acc[mi][ni][r] + bb[ni];
    }
}

// ---------------- Sigmoid attention ----------------
// Q-tile 64/block (wave owns 16 rows), KV-tile 64 staged in LDS with
// source-side XOR swizzle (chunk ^= row&7) -> conflict-free frag reads.
// grid (32, 32) = 1024 blocks.
__global__ __launch_bounds__(256, 4)
void attn_kernel(const unsigned short* __restrict__ qh,
                 const unsigned short* __restrict__ kh,
                 const unsigned short* __restrict__ vT,
                 unsigned short* __restrict__ x) {
  __shared__ unsigned short Klds[64 * 64];   // [kv_row][chunk^swz] 8KB
  __shared__ unsigned short Vlds[64 * 64];   // [d][chunk^swz]     8KB
  __shared__ unsigned short Plds[4 * 16 * 72];  // per-wave [16][72] (144B stride)
  const int t = threadIdx.x, w = t >> 6, l = t & 63, l15 = l & 15, lhi = l >> 4;
  const int qt = blockIdx.x, bh = blockIdx.y, b = bh >> 4;
  const unsigned short* Q = qh + (size_t)bh * SEQ * 64;
  const unsigned short* K = kh + (size_t)bh * SEQ * 64;
  const unsigned short* V = vT + (size_t)bh * 64 * SEQ;
  unsigned short* Pw = &Plds[w * 16 * 72];
  const int qbase = qt * 64 + w * 16;

  bf16x8 qf[2];
#pragma unroll
  for (int kb = 0; kb < 2; ++kb)
    qf[kb] = *(const bf16x8*)&Q[(size_t)(qbase + l15) * 64 + kb * 32 + lhi * 8];

  f32x4 o[4] = {};
  const int r0 = t >> 3, c0 = t & 7, r1 = r0 + 32;

  for (int kv = 0; kv < 32; ++kv) {
    const int kv0 = kv * 64;
    // stage K(8KB)+V(8KB): 4 x 16B per thread, swizzled source
    gload_lds16(K + (size_t)(kv0 + r0) * 64 + (c0 ^ (r0 & 7)) * 8, &Klds[t * 8]);
    gload_lds16(K + (size_t)(kv0 + r1) * 64 + (c0 ^ (r1 & 7)) * 8, &Klds[(t + 256) * 8]);
    gload_lds16(V + (size_t)r0 * SEQ + kv0 + (c0 ^ (r0 & 7)) * 8, &Vlds[t * 8]);
    gload_lds16(V + (size_t)r1 * SEQ + kv0 + (c0 ^ (r1 & 7)) * 8, &Vlds[(t + 256) * 8]);
    __syncthreads();

    // QK^T : s[ni] over kv columns ni*16+l15
    f32x4 s[4] = {};
    __builtin_amdgcn_s_setprio(1);
#pragma unroll
    for (int ni = 0; ni < 4; ++ni) {
#pragma unroll
      for (int kb = 0; kb < 2; ++kb) {
        bf16x8 kf = *(const bf16x8*)&Klds[(ni * 16 + l15) * 64 + (((kb * 4 + lhi) ^ (l15 & 7)) * 8)];
        s[ni] = __builtin_amdgcn_mfma_f32_16x16x32_bf16(qf[kb], kf, s[ni], 0, 0, 0);
      }
    }
    __builtin_amdgcn_s_setprio(0);

    // sigmoid -> bf16 (round-half-up, store high half) -> per-wave LDS
#pragma unroll
    for (int ni = 0; ni < 4; ++ni)
#pragma unroll
      for (int r = 0; r < 4; ++r) {
        float p = __builtin_amdgcn_rcpf(1.0f + __expf(-s[ni][r]));
        Pw[(lhi * 4 + r) * 72 + ni * 16 + l15] = f2bf_rh(p);
      }

    // PV : O[16][64] += P[16][64] @ V[64][64]
    __builtin_amdgcn_s_setprio(1);
#pragma unroll
    for (int kq = 0; kq < 2; ++kq) {
      bf16x8 pf = *(const bf16x8*)&Pw[l15 * 72 + kq * 32 + lhi * 8];
#pragma unroll
      for (int di = 0; di < 4; ++di) {
        bf16x8 vf = *(const bf16x8*)&Vlds[(di * 16 + l15) * 64 + (((kq * 4 + lhi) ^ (l15 & 7)) * 8)];
        o[di] = __builtin_amdgcn_mfma_f32_16x16x32_bf16(pf, vf, o[di], 0, 0, 0);
      }
    }
    __builtin_amdgcn_s_setprio(0);
    __syncthreads();
  }

#pragma unroll
  for (int r = 0; r < 4; ++r) {
    int pos = qbase + lhi * 4 + r;
    size_t base = ((size_t)b * SEQ + pos) * DIM + (bh & 15) * 64;
#pragma unroll
    for (int di = 0; di < 4; ++di)
      x[base + di * 16 + l15] = f2bf(o[di][r]);
  }
}

// ---------------- launch ----------------
extern "C" void kernel_launch(void* const* d_in, const int* in_sizes, int n_in,
                              void* d_out, int out_size, void* d_ws, size_t ws_size,
                              hipStream_t stream) {
  (void)in_sizes; (void)n_in; (void)out_size; (void)ws_size;
  const float* q  = (const float*)d_in[0];
  const float* k  = (const float*)d_in[1];
  const float* v  = (const float*)d_in[2];
  const float* Wq = (const float*)d_in[3];
  const float* Wk = (const float*)d_in[4];
  const float* Wv = (const float*)d_in[5];
  const float* gq = (const float*)d_in[6];
  const float* bq = (const float*)d_in[7];
  const float* gk = (const float*)d_in[8];
  const float* bk = (const float*)d_in[9];
  const float* Wo = (const float*)d_in[10];
  const float* bo = (const float*)d_in[11];
  float* out = (float*)d_out;

  char* ws = (char*)d_ws;
  const size_t MB = 1ull << 20;
  unsigned short* qb  = (unsigned short*)(ws + 0);        // 8MB, reused as x after attn
  unsigned short* kb  = (unsigned short*)(ws + 8  * MB);
  unsigned short* vb  = (unsigned short*)(ws + 16 * MB);
  unsigned short* Wqb = (unsigned short*)(ws + 24 * MB);
  unsigned short* Wkb = (unsigned short*)(ws + 26 * MB);
  unsigned short* Wvb = (unsigned short*)(ws + 28 * MB);
  unsigned short* Wob = (unsigned short*)(ws + 30 * MB);
  unsigned short* qhb = (unsigned short*)(ws + 32 * MB);  // [BH][L][64]
  unsigned short* khb = (unsigned short*)(ws + 40 * MB);  // [BH][L][64]
  unsigned short* vTb = (unsigned short*)(ws + 48 * MB);  // [BH][64][L]
  unsigned short* xb  = qb;

  const int nIn = MTOT * DIM;
  const int nW  = DIM * DIM;

  cvt_f32_bf16<<<dim3(nIn / 1024, 3), 256, 0, stream>>>(q, qb, k, kb, v, vb, nullptr, nullptr, nIn);
  cvt_f32_bf16<<<dim3(nW / 1024, 4), 256, 0, stream>>>(Wq, Wqb, Wk, Wkb, Wv, Wvb, Wo, Wob, nW);

  gemm_qkv<<<dim3(MTOT / 128, NH, 3), 256, 0, stream>>>(qb, kb, vb, Wqb, Wkb, Wvb,
                                                        gq, bq, gk, bk, qhb, khb, vTb);

  attn_kernel<<<dim3(SEQ / 64, BATCH * NH), 256, 0, stream>>>(qhb, khb, vTb, xb);

  gemm_out<<<dim3(MTOT / 128, NH), 256, 0, stream>>>(xb, Wob, bo, out);
}

// Round 3
// 186.443 us; speedup vs baseline: 1.7848x; 1.0027x over previous
//
#include <hip/hip_runtime.h>
#include <stdint.h>

// B=2, L=2048, DIM=1024, 16 heads x 64
#define BATCH 2
#define SEQ   2048
#define DIM   1024
#define NH    16
#define MTOT  (BATCH*SEQ)   // 4096
#define QK_SCALE 0.125f
#define LN_EPS 1e-5f

typedef __bf16 bf16x8 __attribute__((ext_vector_type(8)));
typedef float  f32x4  __attribute__((ext_vector_type(4)));

__device__ __forceinline__ unsigned short f2bf(float f) {
  uint32_t u = __float_as_uint(f);
  u += 0x7fffu + ((u >> 16) & 1u);      // RNE
  return (unsigned short)(u >> 16);
}
__device__ __forceinline__ unsigned short f2bf_rh(float f) {  // round-half-up (P>=0)
  uint32_t u = __float_as_uint(f) + 0x8000u;
  return (unsigned short)(u >> 16);
}

__device__ __forceinline__ void gload_lds16(const void* g, void* lds) {
  __builtin_amdgcn_global_load_lds(
      (const __attribute__((address_space(1))) uint32_t*)g,
      (__attribute__((address_space(3))) uint32_t*)lds, 16, 0, 0);
}

// ---------------- f32 -> bf16 conversion ----------------
__global__ void cvt_f32_bf16(const float* __restrict__ s0, unsigned short* __restrict__ d0,
                             const float* __restrict__ s1, unsigned short* __restrict__ d1,
                             const float* __restrict__ s2, unsigned short* __restrict__ d2,
                             const float* __restrict__ s3, unsigned short* __restrict__ d3,
                             int n) {
  int z = blockIdx.y;
  const float* s = z == 0 ? s0 : z == 1 ? s1 : z == 2 ? s2 : s3;
  unsigned short* d = z == 0 ? d0 : z == 1 ? d1 : z == 2 ? d2 : d3;
  if (s == nullptr) return;
  int i = (blockIdx.x * 256 + threadIdx.x) * 4;
  if (i >= n) return;
  float4 v = *(const float4*)(s + i);
  ushort4 o;
  o.x = f2bf(v.x); o.y = f2bf(v.y); o.z = f2bf(v.z); o.w = f2bf(v.w);
  *(ushort4*)(d + i) = o;
}

// ---------------- fused QKV projections, 2-phase pipelined ----------------
// C[4096][1024] = A @ W^T. BM=BN=128, BK=32, 4 waves (2x2), wave tile 64x64.
// Double-buffered LDS; stage(t+1) issued BEFORE compute(t); ONE barrier/step.
// z=0: LN(gq,bq)*SCALE -> qh [BH][L][64] ; z=1: LN(gk,bk) -> kh ; z=2: vT [BH][64][L]
__global__ __launch_bounds__(256, 2)
void gemm_qkv(const unsigned short* __restrict__ Aq, const unsigned short* __restrict__ Ak,
              const unsigned short* __restrict__ Av,
              const unsigned short* __restrict__ Wqp, const unsigned short* __restrict__ Wkp,
              const unsigned short* __restrict__ Wvp,
              const float* __restrict__ gq, const float* __restrict__ bq,
              const float* __restrict__ gk, const float* __restrict__ bk,
              unsigned short* __restrict__ qh, unsigned short* __restrict__ kh,
              unsigned short* __restrict__ vT) {
  __shared__ unsigned short Asm[2][4096];  // [buf][kb4][128][8] : 8KB each
  __shared__ unsigned short Bsm[2][4096];
  const int z = blockIdx.z;
  const unsigned short* A = z == 0 ? Aq : z == 1 ? Ak : Av;
  const unsigned short* W = z == 0 ? Wqp : z == 1 ? Wkp : Wvp;
  const int t = threadIdx.x, w = t >> 6, l = t & 63, l15 = l & 15, lhi = l >> 4;
  const int wm = w >> 1, wn = w & 1;
  const int m0 = blockIdx.x * 128, n0 = blockIdx.y * 128;
  const int ldrow = t & 127, ldkb = t >> 7;   // staging coords (2 passes)

  f32x4 acc[4][4] = {};

#define STAGE_G(buf, kt) do {                                                     \
    int k0 = (kt) * 32;                                                           \
    gload_lds16(A + (size_t)(m0 + ldrow) * 1024 + k0 + ldkb * 8,                  \
                &Asm[buf][t * 8]);                                                \
    gload_lds16(A + (size_t)(m0 + ldrow) * 1024 + k0 + (ldkb + 2) * 8,            \
                &Asm[buf][(t + 256) * 8]);                                        \
    gload_lds16(W + (size_t)(n0 + ldrow) * 1024 + k0 + ldkb * 8,                  \
                &Bsm[buf][t * 8]);                                                \
    gload_lds16(W + (size_t)(n0 + ldrow) * 1024 + k0 + (ldkb + 2) * 8,            \
                &Bsm[buf][(t + 256) * 8]);                                        \
  } while (0)

  STAGE_G(0, 0);
  __syncthreads();
  for (int kt = 0; kt < 32; ++kt) {
    const int cur = kt & 1;
    if (kt + 1 < 32) STAGE_G(cur ^ 1, kt + 1);
    bf16x8 af[4], bfr[4];
#pragma unroll
    for (int mi = 0; mi < 4; ++mi)
      af[mi] = *(const bf16x8*)&Asm[cur][lhi * 1024 + (wm * 64 + mi * 16 + l15) * 8];
#pragma unroll
    for (int ni = 0; ni < 4; ++ni)
      bfr[ni] = *(const bf16x8*)&Bsm[cur][lhi * 1024 + (wn * 64 + ni * 16 + l15) * 8];
    __builtin_amdgcn_s_setprio(1);
#pragma unroll
    for (int mi = 0; mi < 4; ++mi)
#pragma unroll
      for (int ni = 0; ni < 4; ++ni)
        acc[mi][ni] = __builtin_amdgcn_mfma_f32_16x16x32_bf16(af[mi], bfr[ni], acc[mi][ni], 0, 0, 0);
    __builtin_amdgcn_s_setprio(0);
    __syncthreads();   // drains prefetch vmcnt + guards LDS reuse
  }

  const int h = (n0 >> 6) + wn;   // wave's 64-col half = one head
  if (z == 2) {
#pragma unroll
    for (int mi = 0; mi < 4; ++mi)
#pragma unroll
      for (int r = 0; r < 4; ++r) {
        int gm = m0 + wm * 64 + mi * 16 + lhi * 4 + r;
        int b = gm >> 11, pos = gm & 2047;
#pragma unroll
        for (int ni = 0; ni < 4; ++ni)
          vT[(((size_t)(b * NH + h)) * 64 + ni * 16 + l15) * SEQ + pos] = f2bf(acc[mi][ni][r]);
      }
  } else {
    const float* G  = z ? gk : gq;
    const float* Bt = z ? bk : bq;
    unsigned short* outp = z ? kh : qh;
    const float sc = z ? 1.f : QK_SCALE;
    float g[4], bt[4];
#pragma unroll
    for (int ni = 0; ni < 4; ++ni) { g[ni] = G[ni * 16 + l15]; bt[ni] = Bt[ni * 16 + l15]; }
#pragma unroll
    for (int mi = 0; mi < 4; ++mi)
#pragma unroll
      for (int r = 0; r < 4; ++r) {
        float x[4], s = 0.f, s2 = 0.f;
#pragma unroll
        for (int ni = 0; ni < 4; ++ni) { x[ni] = acc[mi][ni][r]; s += x[ni]; s2 += x[ni] * x[ni]; }
#pragma unroll
        for (int msk = 1; msk < 16; msk <<= 1) {
          s  += __shfl_xor(s,  msk, 64);
          s2 += __shfl_xor(s2, msk, 64);
        }
        float mu = s * (1.f / 64.f);
        float var = s2 * (1.f / 64.f) - mu * mu;
        float rstd = rsqrtf(var + LN_EPS);
        int gm = m0 + wm * 64 + mi * 16 + lhi * 4 + r;
        int b = gm >> 11, pos = gm & 2047;
        size_t base = (((size_t)(b * NH + h)) * SEQ + pos) * 64;
#pragma unroll
        for (int ni = 0; ni < 4; ++ni) {
          float y = ((x[ni] - mu) * rstd * g[ni] + bt[ni]) * sc;
          outp[base + ni * 16 + l15] = f2bf(y);
        }
      }
  }
#undef STAGE_G
}

// ---------------- out projection: out = x @ Wo^T + bo (f32), 2-phase ------
__global__ __launch_bounds__(256, 2)
void gemm_out(const unsigned short* __restrict__ A, const unsigned short* __restrict__ W,
              const float* __restrict__ bias, float* __restrict__ outf) {
  __shared__ unsigned short Asm[2][4096];
  __shared__ unsigned short Bsm[2][4096];
  const int t = threadIdx.x, w = t >> 6, l = t & 63, l15 = l & 15, lhi = l >> 4;
  const int wm = w >> 1, wn = w & 1;
  const int m0 = blockIdx.x * 128, n0 = blockIdx.y * 128;
  const int ldrow = t & 127, ldkb = t >> 7;
  f32x4 acc[4][4] = {};

#define STAGE_G(buf, kt) do {                                                     \
    int k0 = (kt) * 32;                                                           \
    gload_lds16(A + (size_t)(m0 + ldrow) * 1024 + k0 + ldkb * 8,                  \
                &Asm[buf][t * 8]);                                                \
    gload_lds16(A + (size_t)(m0 + ldrow) * 1024 + k0 + (ldkb + 2) * 8,            \
                &Asm[buf][(t + 256) * 8]);                                        \
    gload_lds16(W + (size_t)(n0 + ldrow) * 1024 + k0 + ldkb * 8,                  \
                &Bsm[buf][t * 8]);                                                \
    gload_lds16(W + (size_t)(n0 + ldrow) * 1024 + k0 + (ldkb + 2) * 8,            \
                &Bsm[buf][(t + 256) * 8]);                                        \
  } while (0)

  STAGE_G(0, 0);
  __syncthreads();
  for (int kt = 0; kt < 32; ++kt) {
    const int cur = kt & 1;
    if (kt + 1 < 32) STAGE_G(cur ^ 1, kt + 1);
    bf16x8 af[4], bfr[4];
#pragma unroll
    for (int mi = 0; mi < 4; ++mi)
      af[mi] = *(const bf16x8*)&Asm[cur][lhi * 1024 + (wm * 64 + mi * 16 + l15) * 8];
#pragma unroll
    for (int ni = 0; ni < 4; ++ni)
      bfr[ni] = *(const bf16x8*)&Bsm[cur][lhi * 1024 + (wn * 64 + ni * 16 + l15) * 8];
    __builtin_amdgcn_s_setprio(1);
#pragma unroll
    for (int mi = 0; mi < 4; ++mi)
#pragma unroll
      for (int ni = 0; ni < 4; ++ni)
        acc[mi][ni] = __builtin_amdgcn_mfma_f32_16x16x32_bf16(af[mi], bfr[ni], acc[mi][ni], 0, 0, 0);
    __builtin_amdgcn_s_setprio(0);
    __syncthreads();
  }
#undef STAGE_G
  float bb[4];
#pragma unroll
  for (int ni = 0; ni < 4; ++ni) bb[ni] = bias[n0 + wn * 64 + ni * 16 + l15];
#pragma unroll
  for (int mi = 0; mi < 4; ++mi)
#pragma unroll
    for (int r = 0; r < 4; ++r) {
      int gm = m0 + wm * 64 + mi * 16 + lhi * 4 + r;
      float* op = outf + (size_t)gm * 1024 + n0 + wn * 64 + l15;
#pragma unroll
      for (int ni = 0; ni < 4; ++ni) op[ni * 16] = acc[mi][ni][r] + bb[ni];
    }
}

// ---------------- Sigmoid attention, 2-phase pipelined ----------------
// Q-tile 64/block (wave owns 16 rows), KV-tile 64 double-buffered in LDS
// with source-side XOR swizzle; ONE barrier per kv step.
__global__ __launch_bounds__(256, 3)
void attn_kernel(const unsigned short* __restrict__ qh,
                 const unsigned short* __restrict__ kh,
                 const unsigned short* __restrict__ vT,
                 unsigned short* __restrict__ x) {
  __shared__ unsigned short Klds[2][4096];   // [buf][kv_row][chunk^swz] 8KB
  __shared__ unsigned short Vlds[2][4096];   // [buf][d][chunk^swz]
  __shared__ unsigned short Plds[4 * 16 * 72];  // per-wave [16][72]
  const int t = threadIdx.x, w = t >> 6, l = t & 63, l15 = l & 15, lhi = l >> 4;
  const int qt = blockIdx.x, bh = blockIdx.y, b = bh >> 4;
  const unsigned short* Q = qh + (size_t)bh * SEQ * 64;
  const unsigned short* K = kh + (size_t)bh * SEQ * 64;
  const unsigned short* V = vT + (size_t)bh * 64 * SEQ;
  unsigned short* Pw = &Plds[w * 16 * 72];
  const int qbase = qt * 64 + w * 16;

  bf16x8 qf[2];
#pragma unroll
  for (int kb = 0; kb < 2; ++kb)
    qf[kb] = *(const bf16x8*)&Q[(size_t)(qbase + l15) * 64 + kb * 32 + lhi * 8];

  f32x4 o[4] = {};
  const int r0 = t >> 3, c0 = t & 7, r1 = r0 + 32;

#define STAGE_KV(buf, kv0) do {                                                      \
    gload_lds16(K + (size_t)((kv0) + r0) * 64 + (c0 ^ (r0 & 7)) * 8,                 \
                &Klds[buf][t * 8]);                                                  \
    gload_lds16(K + (size_t)((kv0) + r1) * 64 + (c0 ^ (r1 & 7)) * 8,                 \
                &Klds[buf][(t + 256) * 8]);                                          \
    gload_lds16(V + (size_t)r0 * SEQ + (kv0) + (c0 ^ (r0 & 7)) * 8,                  \
                &Vlds[buf][t * 8]);                                                  \
    gload_lds16(V + (size_t)r1 * SEQ + (kv0) + (c0 ^ (r1 & 7)) * 8,                  \
                &Vlds[buf][(t + 256) * 8]);                                          \
  } while (0)

  STAGE_KV(0, 0);
  __syncthreads();
  for (int kv = 0; kv < 32; ++kv) {
    const int cur = kv & 1;
    if (kv + 1 < 32) STAGE_KV(cur ^ 1, (kv + 1) * 64);

    // QK^T : s[ni] over kv columns ni*16+l15
    f32x4 s[4] = {};
    __builtin_amdgcn_s_setprio(1);
#pragma unroll
    for (int ni = 0; ni < 4; ++ni)
#pragma unroll
      for (int kb = 0; kb < 2; ++kb) {
        bf16x8 kf = *(const bf16x8*)&Klds[cur][(ni * 16 + l15) * 64 + (((kb * 4 + lhi) ^ (l15 & 7)) * 8)];
        s[ni] = __builtin_amdgcn_mfma_f32_16x16x32_bf16(qf[kb], kf, s[ni], 0, 0, 0);
      }
    __builtin_amdgcn_s_setprio(0);

    // sigmoid -> bf16 -> per-wave LDS (C-layout write, A-frag read)
#pragma unroll
    for (int ni = 0; ni < 4; ++ni)
#pragma unroll
      for (int r = 0; r < 4; ++r) {
        float p = __builtin_amdgcn_rcpf(1.0f + __expf(-s[ni][r]));
        Pw[(lhi * 4 + r) * 72 + ni * 16 + l15] = f2bf_rh(p);
      }

    // PV : O[16][64] += P[16][64] @ V[64][64]
    __builtin_amdgcn_s_setprio(1);
#pragma unroll
    for (int kq = 0; kq < 2; ++kq) {
      bf16x8 pf = *(const bf16x8*)&Pw[l15 * 72 + kq * 32 + lhi * 8];
#pragma unroll
      for (int di = 0; di < 4; ++di) {
        bf16x8 vf = *(const bf16x8*)&Vlds[cur][(di * 16 + l15) * 64 + (((kq * 4 + lhi) ^ (l15 & 7)) * 8)];
        o[di] = __builtin_amdgcn_mfma_f32_16x16x32_bf16(pf, vf, o[di], 0, 0, 0);
      }
    }
    __builtin_amdgcn_s_setprio(0);
    __syncthreads();   // prefetch landed + everyone done with cur
  }
#undef STAGE_KV

#pragma unroll
  for (int r = 0; r < 4; ++r) {
    int pos = qbase + lhi * 4 + r;
    size_t base = ((size_t)b * SEQ + pos) * DIM + (bh & 15) * 64;
#pragma unroll
    for (int di = 0; di < 4; ++di)
      x[base + di * 16 + l15] = f2bf(o[di][r]);
  }
}

// ---------------- launch ----------------
extern "C" void kernel_launch(void* const* d_in, const int* in_sizes, int n_in,
                              void* d_out, int out_size, void* d_ws, size_t ws_size,
                              hipStream_t stream) {
  (void)in_sizes; (void)n_in; (void)out_size; (void)ws_size;
  const float* q  = (const float*)d_in[0];
  const float* k  = (const float*)d_in[1];
  const float* v  = (const float*)d_in[2];
  const float* Wq = (const float*)d_in[3];
  const float* Wk = (const float*)d_in[4];
  const float* Wv = (const float*)d_in[5];
  const float* gq = (const float*)d_in[6];
  const float* bq = (const float*)d_in[7];
  const float* gk = (const float*)d_in[8];
  const float* bk = (const float*)d_in[9];
  const float* Wo = (const float*)d_in[10];
  const float* bo = (const float*)d_in[11];
  float* out = (float*)d_out;

  char* ws = (char*)d_ws;
  const size_t MB = 1ull << 20;
  unsigned short* qb  = (unsigned short*)(ws + 0);        // 8MB, reused as x after attn
  unsigned short* kb  = (unsigned short*)(ws + 8  * MB);
  unsigned short* vb  = (unsigned short*)(ws + 16 * MB);
  unsigned short* Wqb = (unsigned short*)(ws + 24 * MB);
  unsigned short* Wkb = (unsigned short*)(ws + 26 * MB);
  unsigned short* Wvb = (unsigned short*)(ws + 28 * MB);
  unsigned short* Wob = (unsigned short*)(ws + 30 * MB);
  unsigned short* qhb = (unsigned short*)(ws + 32 * MB);  // [BH][L][64]
  unsigned short* khb = (unsigned short*)(ws + 40 * MB);  // [BH][L][64]
  unsigned short* vTb = (unsigned short*)(ws + 48 * MB);  // [BH][64][L]
  unsigned short* xb  = qb;

  const int nIn = MTOT * DIM;
  const int nW  = DIM * DIM;

  cvt_f32_bf16<<<dim3(nIn / 1024, 3), 256, 0, stream>>>(q, qb, k, kb, v, vb, nullptr, nullptr, nIn);
  cvt_f32_bf16<<<dim3(nW / 1024, 4), 256, 0, stream>>>(Wq, Wqb, Wk, Wkb, Wv, Wvb, Wo, Wob, nW);

  gemm_qkv<<<dim3(MTOT / 128, DIM / 128, 3), 256, 0, stream>>>(qb, kb, vb, Wqb, Wkb, Wvb,
                                                               gq, bq, gk, bk, qhb, khb, vTb);

  attn_kernel<<<dim3(SEQ / 64, BATCH * NH), 256, 0, stream>>>(qhb, khb, vTb, xb);

  gemm_out<<<dim3(MTOT / 128, DIM / 128), 256, 0, stream>>>(xb, Wob, bo, out);
}

// Round 4
// 167.551 us; speedup vs baseline: 1.9860x; 1.1128x over previous
//
#include <hip/hip_runtime.h>
#include <stdint.h>

// B=2, L=2048, DIM=1024, 16 heads x 64
#define BATCH 2
#define SEQ   2048
#define DIM   1024
#define NH    16
#define MTOT  (BATCH*SEQ)   // 4096
#define LN_EPS 1e-5f
// Q scale folded with -log2(e): sigmoid(s) = rcp(1 + exp2(s*-log2e))
#define Q_FOLD_SCALE (-0.1803368801111204f)   // 0.125 * -1.4426950408889634

typedef __bf16 bf16x8 __attribute__((ext_vector_type(8)));
typedef float  f32x4  __attribute__((ext_vector_type(4)));

__device__ __forceinline__ unsigned short f2bf(float f) {
  uint32_t u = __float_as_uint(f);
  u += 0x7fffu + ((u >> 16) & 1u);      // RNE
  return (unsigned short)(u >> 16);
}
__device__ __forceinline__ unsigned short f2bf_rh(float f) {  // round-half-up (P>=0)
  uint32_t u = __float_as_uint(f) + 0x8000u;
  return (unsigned short)(u >> 16);
}

__device__ __forceinline__ void gload_lds16(const void* g, void* lds) {
  __builtin_amdgcn_global_load_lds(
      (const __attribute__((address_space(1))) uint32_t*)g,
      (__attribute__((address_space(3))) uint32_t*)lds, 16, 0, 0);
}

#define VMCNT(n) asm volatile("s_waitcnt vmcnt(" #n ")" ::: "memory")
#define BAR() do { __builtin_amdgcn_s_barrier(); __builtin_amdgcn_sched_barrier(0); } while (0)

// ---------------- f32 -> bf16 conversion ----------------
__global__ void cvt_f32_bf16(const float* __restrict__ s0, unsigned short* __restrict__ d0,
                             const float* __restrict__ s1, unsigned short* __restrict__ d1,
                             const float* __restrict__ s2, unsigned short* __restrict__ d2,
                             const float* __restrict__ s3, unsigned short* __restrict__ d3,
                             int n) {
  int z = blockIdx.y;
  const float* s = z == 0 ? s0 : z == 1 ? s1 : z == 2 ? s2 : s3;
  unsigned short* d = z == 0 ? d0 : z == 1 ? d1 : z == 2 ? d2 : d3;
  if (s == nullptr) return;
  int i = (blockIdx.x * 256 + threadIdx.x) * 4;
  if (i >= n) return;
  float4 v = *(const float4*)(s + i);
  ushort4 o;
  o.x = f2bf(v.x); o.y = f2bf(v.y); o.z = f2bf(v.z); o.w = f2bf(v.w);
  *(ushort4*)(d + i) = o;
}

// ---------------- fused QKV projections, counted-vmcnt 2-phase ----------------
// C[4096][1024] = A @ W^T. BM=BN=128, BK=32, 4 waves (2x2), wave tile 64x64.
// z=0: LN(gq,bq)*Q_FOLD_SCALE -> qh ; z=1: LN(gk,bk) -> kh ; z=2: vT [BH][64][L]
__global__ __launch_bounds__(256, 2)
void gemm_qkv(const unsigned short* __restrict__ Aq, const unsigned short* __restrict__ Ak,
              const unsigned short* __restrict__ Av,
              const unsigned short* __restrict__ Wqp, const unsigned short* __restrict__ Wkp,
              const unsigned short* __restrict__ Wvp,
              const float* __restrict__ gq, const float* __restrict__ bq,
              const float* __restrict__ gk, const float* __restrict__ bk,
              unsigned short* __restrict__ qh, unsigned short* __restrict__ kh,
              unsigned short* __restrict__ vT) {
  __shared__ unsigned short Asm[2][4096];  // [buf][kb4][128][8]
  __shared__ unsigned short Bsm[2][4096];
  const int z = blockIdx.z;
  const unsigned short* A = z == 0 ? Aq : z == 1 ? Ak : Av;
  const unsigned short* W = z == 0 ? Wqp : z == 1 ? Wkp : Wvp;
  const int t = threadIdx.x, w = t >> 6, l = t & 63, l15 = l & 15, lhi = l >> 4;
  const int wm = w >> 1, wn = w & 1;
  const int m0 = blockIdx.x * 128, n0 = blockIdx.y * 128;
  const int ldrow = t & 127, ldkb = t >> 7;

  f32x4 acc[4][4] = {};

#define STAGE_G(buf, kt) do {                                                     \
    int k0 = (kt) * 32;                                                           \
    gload_lds16(A + (size_t)(m0 + ldrow) * 1024 + k0 + ldkb * 8,                  \
                &Asm[buf][t * 8]);                                                \
    gload_lds16(A + (size_t)(m0 + ldrow) * 1024 + k0 + (ldkb + 2) * 8,            \
                &Asm[buf][(t + 256) * 8]);                                        \
    gload_lds16(W + (size_t)(n0 + ldrow) * 1024 + k0 + ldkb * 8,                  \
                &Bsm[buf][t * 8]);                                                \
    gload_lds16(W + (size_t)(n0 + ldrow) * 1024 + k0 + (ldkb + 2) * 8,            \
                &Bsm[buf][(t + 256) * 8]);                                        \
  } while (0)

  STAGE_G(0, 0);
  for (int kt = 0; kt < 32; ++kt) {
    const int cur = kt & 1;
    if (kt + 1 < 32) { STAGE_G(cur ^ 1, kt + 1); VMCNT(4); }
    else             { VMCNT(0); }
    BAR();                       // all waves' cur-tile loads landed
    bf16x8 af[4], bfr[4];
#pragma unroll
    for (int mi = 0; mi < 4; ++mi)
      af[mi] = *(const bf16x8*)&Asm[cur][lhi * 1024 + (wm * 64 + mi * 16 + l15) * 8];
#pragma unroll
    for (int ni = 0; ni < 4; ++ni)
      bfr[ni] = *(const bf16x8*)&Bsm[cur][lhi * 1024 + (wn * 64 + ni * 16 + l15) * 8];
    __builtin_amdgcn_s_setprio(1);
#pragma unroll
    for (int mi = 0; mi < 4; ++mi)
#pragma unroll
      for (int ni = 0; ni < 4; ++ni)
        acc[mi][ni] = __builtin_amdgcn_mfma_f32_16x16x32_bf16(af[mi], bfr[ni], acc[mi][ni], 0, 0, 0);
    __builtin_amdgcn_s_setprio(0);
    BAR();                       // readers done before buf reuse
  }
#undef STAGE_G

  const int h = (n0 >> 6) + wn;
  if (z == 2) {
#pragma unroll
    for (int mi = 0; mi < 4; ++mi)
#pragma unroll
      for (int r = 0; r < 4; ++r) {
        int gm = m0 + wm * 64 + mi * 16 + lhi * 4 + r;
        int b = gm >> 11, pos = gm & 2047;
#pragma unroll
        for (int ni = 0; ni < 4; ++ni)
          vT[(((size_t)(b * NH + h)) * 64 + ni * 16 + l15) * SEQ + pos] = f2bf(acc[mi][ni][r]);
      }
  } else {
    const float* G  = z ? gk : gq;
    const float* Bt = z ? bk : bq;
    unsigned short* outp = z ? kh : qh;
    const float sc = z ? 1.f : Q_FOLD_SCALE;
    float g[4], bt[4];
#pragma unroll
    for (int ni = 0; ni < 4; ++ni) { g[ni] = G[ni * 16 + l15]; bt[ni] = Bt[ni * 16 + l15]; }
#pragma unroll
    for (int mi = 0; mi < 4; ++mi)
#pragma unroll
      for (int r = 0; r < 4; ++r) {
        float x[4], s = 0.f, s2 = 0.f;
#pragma unroll
        for (int ni = 0; ni < 4; ++ni) { x[ni] = acc[mi][ni][r]; s += x[ni]; s2 += x[ni] * x[ni]; }
#pragma unroll
        for (int msk = 1; msk < 16; msk <<= 1) {
          s  += __shfl_xor(s,  msk, 64);
          s2 += __shfl_xor(s2, msk, 64);
        }
        float mu = s * (1.f / 64.f);
        float var = s2 * (1.f / 64.f) - mu * mu;
        float rstd = rsqrtf(var + LN_EPS);
        int gm = m0 + wm * 64 + mi * 16 + lhi * 4 + r;
        int b = gm >> 11, pos = gm & 2047;
        size_t base = (((size_t)(b * NH + h)) * SEQ + pos) * 64;
#pragma unroll
        for (int ni = 0; ni < 4; ++ni) {
          float y = ((x[ni] - mu) * rstd * g[ni] + bt[ni]) * sc;
          outp[base + ni * 16 + l15] = f2bf(y);
        }
      }
  }
}

// ---------------- out projection: out = x @ Wo^T + bo (f32) ----------------
__global__ __launch_bounds__(256, 2)
void gemm_out(const unsigned short* __restrict__ A, const unsigned short* __restrict__ W,
              const float* __restrict__ bias, float* __restrict__ outf) {
  __shared__ unsigned short Asm[2][4096];
  __shared__ unsigned short Bsm[2][4096];
  const int t = threadIdx.x, w = t >> 6, l = t & 63, l15 = l & 15, lhi = l >> 4;
  const int wm = w >> 1, wn = w & 1;
  const int m0 = blockIdx.x * 128, n0 = blockIdx.y * 128;
  const int ldrow = t & 127, ldkb = t >> 7;
  f32x4 acc[4][4] = {};

#define STAGE_G(buf, kt) do {                                                     \
    int k0 = (kt) * 32;                                                           \
    gload_lds16(A + (size_t)(m0 + ldrow) * 1024 + k0 + ldkb * 8,                  \
                &Asm[buf][t * 8]);                                                \
    gload_lds16(A + (size_t)(m0 + ldrow) * 1024 + k0 + (ldkb + 2) * 8,            \
                &Asm[buf][(t + 256) * 8]);                                        \
    gload_lds16(W + (size_t)(n0 + ldrow) * 1024 + k0 + ldkb * 8,                  \
                &Bsm[buf][t * 8]);                                                \
    gload_lds16(W + (size_t)(n0 + ldrow) * 1024 + k0 + (ldkb + 2) * 8,            \
                &Bsm[buf][(t + 256) * 8]);                                        \
  } while (0)

  STAGE_G(0, 0);
  for (int kt = 0; kt < 32; ++kt) {
    const int cur = kt & 1;
    if (kt + 1 < 32) { STAGE_G(cur ^ 1, kt + 1); VMCNT(4); }
    else             { VMCNT(0); }
    BAR();
    bf16x8 af[4], bfr[4];
#pragma unroll
    for (int mi = 0; mi < 4; ++mi)
      af[mi] = *(const bf16x8*)&Asm[cur][lhi * 1024 + (wm * 64 + mi * 16 + l15) * 8];
#pragma unroll
    for (int ni = 0; ni < 4; ++ni)
      bfr[ni] = *(const bf16x8*)&Bsm[cur][lhi * 1024 + (wn * 64 + ni * 16 + l15) * 8];
    __builtin_amdgcn_s_setprio(1);
#pragma unroll
    for (int mi = 0; mi < 4; ++mi)
#pragma unroll
      for (int ni = 0; ni < 4; ++ni)
        acc[mi][ni] = __builtin_amdgcn_mfma_f32_16x16x32_bf16(af[mi], bfr[ni], acc[mi][ni], 0, 0, 0);
    __builtin_amdgcn_s_setprio(0);
    BAR();
  }
#undef STAGE_G
  float bb[4];
#pragma unroll
  for (int ni = 0; ni < 4; ++ni) bb[ni] = bias[n0 + wn * 64 + ni * 16 + l15];
#pragma unroll
  for (int mi = 0; mi < 4; ++mi)
#pragma unroll
    for (int r = 0; r < 4; ++r) {
      int gm = m0 + wm * 64 + mi * 16 + lhi * 4 + r;
      float* op = outf + (size_t)gm * 1024 + n0 + wn * 64 + l15;
#pragma unroll
      for (int ni = 0; ni < 4; ++ni) op[ni * 16] = acc[mi][ni][r] + bb[ni];
    }
}

// ---------------- Sigmoid attention ----------------
// Q-tile 128/block (wave owns 32 rows -> halves K/V LDS frag traffic),
// KV-tile 64 double-buffered, counted-vmcnt 2-barrier loop.
// grid (16, 32) = 512 blocks.
__global__ __launch_bounds__(256, 2)
void attn_kernel(const unsigned short* __restrict__ qh,
                 const unsigned short* __restrict__ kh,
                 const unsigned short* __restrict__ vT,
                 unsigned short* __restrict__ x) {
  __shared__ unsigned short Klds[2][4096];      // [buf][kv_row][chunk^swz]
  __shared__ unsigned short Vlds[2][4096];      // [buf][d][chunk^swz]
  __shared__ unsigned short Plds[4 * 32 * 72];  // per-wave [32][72] (144B stride)
  const int t = threadIdx.x, w = t >> 6, l = t & 63, l15 = l & 15, lhi = l >> 4;
  const int qt = blockIdx.x, bh = blockIdx.y, b = bh >> 4;
  const unsigned short* Q = qh + (size_t)bh * SEQ * 64;
  const unsigned short* K = kh + (size_t)bh * SEQ * 64;
  const unsigned short* V = vT + (size_t)bh * 64 * SEQ;
  unsigned short* Pw = &Plds[w * 32 * 72];
  const int qbase = qt * 128 + w * 32;

  bf16x8 qf[2][2];
#pragma unroll
  for (int mi = 0; mi < 2; ++mi)
#pragma unroll
    for (int kb = 0; kb < 2; ++kb)
      qf[mi][kb] = *(const bf16x8*)&Q[(size_t)(qbase + mi * 16 + l15) * 64 + kb * 32 + lhi * 8];

  f32x4 o[2][4] = {};
  const int r0 = t >> 3, c0 = t & 7, r1 = r0 + 32;

#define STAGE_KV(buf, kv0) do {                                                      \
    gload_lds16(K + (size_t)((kv0) + r0) * 64 + (c0 ^ (r0 & 7)) * 8,                 \
                &Klds[buf][t * 8]);                                                  \
    gload_lds16(K + (size_t)((kv0) + r1) * 64 + (c0 ^ (r1 & 7)) * 8,                 \
                &Klds[buf][(t + 256) * 8]);                                          \
    gload_lds16(V + (size_t)r0 * SEQ + (kv0) + (c0 ^ (r0 & 7)) * 8,                  \
                &Vlds[buf][t * 8]);                                                  \
    gload_lds16(V + (size_t)r1 * SEQ + (kv0) + (c0 ^ (r1 & 7)) * 8,                  \
                &Vlds[buf][(t + 256) * 8]);                                          \
  } while (0)

  STAGE_KV(0, 0);
  for (int kv = 0; kv < 32; ++kv) {
    const int cur = kv & 1;
    if (kv + 1 < 32) { STAGE_KV(cur ^ 1, (kv + 1) * 64); VMCNT(4); }
    else             { VMCNT(0); }
    BAR();                        // cur K/V tile valid in LDS

    // QK^T (Q pre-scaled by -0.125*log2e): s[mi][ni]
    f32x4 s[2][4] = {};
    __builtin_amdgcn_s_setprio(1);
#pragma unroll
    for (int ni = 0; ni < 4; ++ni)
#pragma unroll
      for (int kb = 0; kb < 2; ++kb) {
        bf16x8 kf = *(const bf16x8*)&Klds[cur][(ni * 16 + l15) * 64 + (((kb * 4 + lhi) ^ (l15 & 7)) * 8)];
        s[0][ni] = __builtin_amdgcn_mfma_f32_16x16x32_bf16(qf[0][kb], kf, s[0][ni], 0, 0, 0);
        s[1][ni] = __builtin_amdgcn_mfma_f32_16x16x32_bf16(qf[1][kb], kf, s[1][ni], 0, 0, 0);
      }
    __builtin_amdgcn_s_setprio(0);

    // sigmoid = rcp(1 + exp2(s~)) -> bf16 -> per-wave LDS
#pragma unroll
    for (int mi = 0; mi < 2; ++mi)
#pragma unroll
      for (int ni = 0; ni < 4; ++ni)
#pragma unroll
        for (int r = 0; r < 4; ++r) {
          float p = __builtin_amdgcn_rcpf(1.0f + __builtin_amdgcn_exp2f(s[mi][ni][r]));
          Pw[(mi * 16 + lhi * 4 + r) * 72 + ni * 16 + l15] = f2bf_rh(p);
        }

    // PV : O[32][64] += P[32][64] @ V[64][64]
    __builtin_amdgcn_s_setprio(1);
#pragma unroll
    for (int kq = 0; kq < 2; ++kq) {
      bf16x8 pf0 = *(const bf16x8*)&Pw[l15 * 72 + kq * 32 + lhi * 8];
      bf16x8 pf1 = *(const bf16x8*)&Pw[(16 + l15) * 72 + kq * 32 + lhi * 8];
#pragma unroll
      for (int di = 0; di < 4; ++di) {
        bf16x8 vf = *(const bf16x8*)&Vlds[cur][(di * 16 + l15) * 64 + (((kq * 4 + lhi) ^ (l15 & 7)) * 8)];
        o[0][di] = __builtin_amdgcn_mfma_f32_16x16x32_bf16(pf0, vf, o[0][di], 0, 0, 0);
        o[1][di] = __builtin_amdgcn_mfma_f32_16x16x32_bf16(pf1, vf, o[1][di], 0, 0, 0);
      }
    }
    __builtin_amdgcn_s_setprio(0);
    BAR();                        // readers done before buf reuse
  }
#undef STAGE_KV

#pragma unroll
  for (int mi = 0; mi < 2; ++mi)
#pragma unroll
    for (int r = 0; r < 4; ++r) {
      int pos = qbase + mi * 16 + lhi * 4 + r;
      size_t base = ((size_t)b * SEQ + pos) * DIM + (bh & 15) * 64;
#pragma unroll
      for (int di = 0; di < 4; ++di)
        x[base + di * 16 + l15] = f2bf(o[mi][di][r]);
    }
}

// ---------------- launch ----------------
extern "C" void kernel_launch(void* const* d_in, const int* in_sizes, int n_in,
                              void* d_out, int out_size, void* d_ws, size_t ws_size,
                              hipStream_t stream) {
  (void)in_sizes; (void)n_in; (void)out_size; (void)ws_size;
  const float* q  = (const float*)d_in[0];
  const float* k  = (const float*)d_in[1];
  const float* v  = (const float*)d_in[2];
  const float* Wq = (const float*)d_in[3];
  const float* Wk = (const float*)d_in[4];
  const float* Wv = (const float*)d_in[5];
  const float* gq = (const float*)d_in[6];
  const float* bq = (const float*)d_in[7];
  const float* gk = (const float*)d_in[8];
  const float* bk = (const float*)d_in[9];
  const float* Wo = (const float*)d_in[10];
  const float* bo = (const float*)d_in[11];
  float* out = (float*)d_out;

  char* ws = (char*)d_ws;
  const size_t MB = 1ull << 20;
  unsigned short* qb  = (unsigned short*)(ws + 0);        // 8MB, reused as x after attn
  unsigned short* kb  = (unsigned short*)(ws + 8  * MB);
  unsigned short* vb  = (unsigned short*)(ws + 16 * MB);
  unsigned short* Wqb = (unsigned short*)(ws + 24 * MB);
  unsigned short* Wkb = (unsigned short*)(ws + 26 * MB);
  unsigned short* Wvb = (unsigned short*)(ws + 28 * MB);
  unsigned short* Wob = (unsigned short*)(ws + 30 * MB);
  unsigned short* qhb = (unsigned short*)(ws + 32 * MB);  // [BH][L][64]
  unsigned short* khb = (unsigned short*)(ws + 40 * MB);  // [BH][L][64]
  unsigned short* vTb = (unsigned short*)(ws + 48 * MB);  // [BH][64][L]
  unsigned short* xb  = qb;

  const int nIn = MTOT * DIM;
  const int nW  = DIM * DIM;

  cvt_f32_bf16<<<dim3(nIn / 1024, 3), 256, 0, stream>>>(q, qb, k, kb, v, vb, nullptr, nullptr, nIn);
  cvt_f32_bf16<<<dim3(nW / 1024, 4), 256, 0, stream>>>(Wq, Wqb, Wk, Wkb, Wv, Wvb, Wo, Wob, nW);

  gemm_qkv<<<dim3(MTOT / 128, DIM / 128, 3), 256, 0, stream>>>(qb, kb, vb, Wqb, Wkb, Wvb,
                                                               gq, bq, gk, bk, qhb, khb, vTb);

  attn_kernel<<<dim3(SEQ / 128, BATCH * NH), 256, 0, stream>>>(qhb, khb, vTb, xb);

  gemm_out<<<dim3(MTOT / 128, DIM / 128), 256, 0, stream>>>(xb, Wob, bo, out);
}

// Round 7
// 159.508 us; speedup vs baseline: 2.0861x; 1.0504x over previous
//
#include <hip/hip_runtime.h>
#include <stdint.h>

// B=2, L=2048, DIM=1024, 16 heads x 64
#define BATCH 2
#define SEQ   2048
#define DIM   1024
#define NH    16
#define MTOT  (BATCH*SEQ)   // 4096
#define LN_EPS 1e-5f
// Q scale folded with -log2(e): sigmoid(s) = rcp(1 + exp2(s*-log2e))
#define Q_FOLD_SCALE (-0.1803368801111204f)   // 0.125 * -1.4426950408889634

typedef __bf16 bf16x8 __attribute__((ext_vector_type(8)));
typedef float  f32x4  __attribute__((ext_vector_type(4)));

__device__ __forceinline__ unsigned short f2bf(float f) {
  uint32_t u = __float_as_uint(f);
  u += 0x7fffu + ((u >> 16) & 1u);      // RNE
  return (unsigned short)(u >> 16);
}
__device__ __forceinline__ unsigned short f2bf_rh(float f) {  // round-half-up (P>=0)
  uint32_t u = __float_as_uint(f) + 0x8000u;
  return (unsigned short)(u >> 16);
}

__device__ __forceinline__ void gload_lds16(const void* g, void* lds) {
  __builtin_amdgcn_global_load_lds(
      (const __attribute__((address_space(1))) uint32_t*)g,
      (__attribute__((address_space(3))) uint32_t*)lds, 16, 0, 0);
}

#define VMCNT(n) asm volatile("s_waitcnt vmcnt(" #n ")" ::: "memory")
#define BAR() do { __builtin_amdgcn_s_barrier(); __builtin_amdgcn_sched_barrier(0); } while (0)
// Fence between LDS writes and subsequent LDS reads of the same buffer (TBAA-
// distinct types on Plds have no alias edge; block compile-time motion + wait).
#define DSFENCE() do {                                        \
    __builtin_amdgcn_sched_barrier(0);                        \
    asm volatile("s_waitcnt lgkmcnt(0)" ::: "memory");        \
    __builtin_amdgcn_sched_barrier(0);                        \
  } while (0)
#define ROT3(a, b, c) do { unsigned short* _tmp = (a); (a) = (b); (b) = (c); (c) = _tmp; } while (0)

// ---------------- f32 -> bf16 conversion ----------------
__global__ void cvt_f32_bf16(const float* __restrict__ s0, unsigned short* __restrict__ d0,
                             const float* __restrict__ s1, unsigned short* __restrict__ d1,
                             const float* __restrict__ s2, unsigned short* __restrict__ d2,
                             const float* __restrict__ s3, unsigned short* __restrict__ d3,
                             int n) {
  int z = blockIdx.y;
  const float* s = z == 0 ? s0 : z == 1 ? s1 : z == 2 ? s2 : s3;
  unsigned short* d = z == 0 ? d0 : z == 1 ? d1 : z == 2 ? d2 : d3;
  if (s == nullptr) return;
  int i = (blockIdx.x * 256 + threadIdx.x) * 4;
  if (i >= n) return;
  float4 v = *(const float4*)(s + i);
  ushort4 o;
  o.x = f2bf(v.x); o.y = f2bf(v.y); o.z = f2bf(v.z); o.w = f2bf(v.w);
  *(ushort4*)(d + i) = o;
}

// ---------------- fused QKV projections: triple-buffer, ONE barrier/step ----
// C[4096][1024] = A @ W^T. BM=BN=128, BK=32, 4 waves (2x2), wave tile 64x64.
// Slot rotation: step t stages tile t+1 into nxt, reads cur, 1 BAR/step.
// WAR-safe: overwriter of a slot (step t+1) and its last readers (step t-1)
// are separated by step t's barrier.
__global__ __launch_bounds__(256, 3)
void gemm_qkv(const unsigned short* __restrict__ Aq, const unsigned short* __restrict__ Ak,
              const unsigned short* __restrict__ Av,
              const unsigned short* __restrict__ Wqp, const unsigned short* __restrict__ Wkp,
              const unsigned short* __restrict__ Wvp,
              const float* __restrict__ gq, const float* __restrict__ bq,
              const float* __restrict__ gk, const float* __restrict__ bk,
              unsigned short* __restrict__ qh, unsigned short* __restrict__ kh,
              unsigned short* __restrict__ vT) {
  __shared__ unsigned short Asm[3][4096];  // [slot][kb4][128][8] 8KB each
  __shared__ unsigned short Bsm[3][4096];
  const int z = blockIdx.z;
  const unsigned short* A = z == 0 ? Aq : z == 1 ? Ak : Av;
  const unsigned short* W = z == 0 ? Wqp : z == 1 ? Wkp : Wvp;
  const int t = threadIdx.x, w = t >> 6, l = t & 63, l15 = l & 15, lhi = l >> 4;
  const int wm = w >> 1, wn = w & 1;
  const int m0 = blockIdx.x * 128, n0 = blockIdx.y * 128;
  const int ldrow = t & 127, ldkb = t >> 7;

  unsigned short *ac = &Asm[0][0], *an = &Asm[1][0], *af_ = &Asm[2][0];
  unsigned short *bc = &Bsm[0][0], *bn = &Bsm[1][0], *bf_ = &Bsm[2][0];

  f32x4 acc[4][4] = {};

#define STAGE_G(ap, bp, kt) do {                                                  \
    int k0 = (kt) * 32;                                                           \
    gload_lds16(A + (size_t)(m0 + ldrow) * 1024 + k0 + ldkb * 8, (ap) + t * 8);   \
    gload_lds16(A + (size_t)(m0 + ldrow) * 1024 + k0 + (ldkb + 2) * 8,            \
                (ap) + (t + 256) * 8);                                            \
    gload_lds16(W + (size_t)(n0 + ldrow) * 1024 + k0 + ldkb * 8, (bp) + t * 8);   \
    gload_lds16(W + (size_t)(n0 + ldrow) * 1024 + k0 + (ldkb + 2) * 8,            \
                (bp) + (t + 256) * 8);                                            \
  } while (0)

  STAGE_G(ac, bc, 0);
  for (int kt = 0; kt < 32; ++kt) {
    if (kt + 1 < 32) { STAGE_G(an, bn, kt + 1); VMCNT(4); }
    else             { VMCNT(0); }
    BAR();                       // cur tile landed for ALL waves
    bf16x8 afr[4], bfr[4];
#pragma unroll
    for (int mi = 0; mi < 4; ++mi)
      afr[mi] = *(const bf16x8*)&ac[lhi * 1024 + (wm * 64 + mi * 16 + l15) * 8];
#pragma unroll
    for (int ni = 0; ni < 4; ++ni)
      bfr[ni] = *(const bf16x8*)&bc[lhi * 1024 + (wn * 64 + ni * 16 + l15) * 8];
    __builtin_amdgcn_s_setprio(1);
#pragma unroll
    for (int mi = 0; mi < 4; ++mi)
#pragma unroll
      for (int ni = 0; ni < 4; ++ni)
        acc[mi][ni] = __builtin_amdgcn_mfma_f32_16x16x32_bf16(afr[mi], bfr[ni], acc[mi][ni], 0, 0, 0);
    __builtin_amdgcn_s_setprio(0);
    ROT3(ac, an, af_);
    ROT3(bc, bn, bf_);
  }
#undef STAGE_G

  const int h = (n0 >> 6) + wn;
  if (z == 2) {
#pragma unroll
    for (int mi = 0; mi < 4; ++mi)
#pragma unroll
      for (int r = 0; r < 4; ++r) {
        int gm = m0 + wm * 64 + mi * 16 + lhi * 4 + r;
        int b = gm >> 11, pos = gm & 2047;
#pragma unroll
        for (int ni = 0; ni < 4; ++ni)
          vT[(((size_t)(b * NH + h)) * 64 + ni * 16 + l15) * SEQ + pos] = f2bf(acc[mi][ni][r]);
      }
  } else {
    const float* G  = z ? gk : gq;
    const float* Bt = z ? bk : bq;
    unsigned short* outp = z ? kh : qh;
    const float sc = z ? 1.f : Q_FOLD_SCALE;
    float g[4], bt[4];
#pragma unroll
    for (int ni = 0; ni < 4; ++ni) { g[ni] = G[ni * 16 + l15]; bt[ni] = Bt[ni * 16 + l15]; }
#pragma unroll
    for (int mi = 0; mi < 4; ++mi)
#pragma unroll
      for (int r = 0; r < 4; ++r) {
        float x[4], s = 0.f, s2 = 0.f;
#pragma unroll
        for (int ni = 0; ni < 4; ++ni) { x[ni] = acc[mi][ni][r]; s += x[ni]; s2 += x[ni] * x[ni]; }
#pragma unroll
        for (int msk = 1; msk < 16; msk <<= 1) {
          s  += __shfl_xor(s,  msk, 64);
          s2 += __shfl_xor(s2, msk, 64);
        }
        float mu = s * (1.f / 64.f);
        float var = s2 * (1.f / 64.f) - mu * mu;
        float rstd = rsqrtf(var + LN_EPS);
        int gm = m0 + wm * 64 + mi * 16 + lhi * 4 + r;
        int b = gm >> 11, pos = gm & 2047;
        size_t base = (((size_t)(b * NH + h)) * SEQ + pos) * 64;
#pragma unroll
        for (int ni = 0; ni < 4; ++ni) {
          float y = ((x[ni] - mu) * rstd * g[ni] + bt[ni]) * sc;
          outp[base + ni * 16 + l15] = f2bf(y);
        }
      }
  }
}

// ---------------- out projection: out = x @ Wo^T + bo (f32), triple-buffer ----
__global__ __launch_bounds__(256, 3)
void gemm_out(const unsigned short* __restrict__ A, const unsigned short* __restrict__ W,
              const float* __restrict__ bias, float* __restrict__ outf) {
  __shared__ unsigned short Asm[3][4096];
  __shared__ unsigned short Bsm[3][4096];
  const int t = threadIdx.x, w = t >> 6, l = t & 63, l15 = l & 15, lhi = l >> 4;
  const int wm = w >> 1, wn = w & 1;
  const int m0 = blockIdx.x * 128, n0 = blockIdx.y * 128;
  const int ldrow = t & 127, ldkb = t >> 7;

  unsigned short *ac = &Asm[0][0], *an = &Asm[1][0], *af_ = &Asm[2][0];
  unsigned short *bc = &Bsm[0][0], *bn = &Bsm[1][0], *bf_ = &Bsm[2][0];
  f32x4 acc[4][4] = {};

#define STAGE_G(ap, bp, kt) do {                                                  \
    int k0 = (kt) * 32;                                                           \
    gload_lds16(A + (size_t)(m0 + ldrow) * 1024 + k0 + ldkb * 8, (ap) + t * 8);   \
    gload_lds16(A + (size_t)(m0 + ldrow) * 1024 + k0 + (ldkb + 2) * 8,            \
                (ap) + (t + 256) * 8);                                            \
    gload_lds16(W + (size_t)(n0 + ldrow) * 1024 + k0 + ldkb * 8, (bp) + t * 8);   \
    gload_lds16(W + (size_t)(n0 + ldrow) * 1024 + k0 + (ldkb + 2) * 8,            \
                (bp) + (t + 256) * 8);                                            \
  } while (0)

  STAGE_G(ac, bc, 0);
  for (int kt = 0; kt < 32; ++kt) {
    if (kt + 1 < 32) { STAGE_G(an, bn, kt + 1); VMCNT(4); }
    else             { VMCNT(0); }
    BAR();
    bf16x8 afr[4], bfr[4];
#pragma unroll
    for (int mi = 0; mi < 4; ++mi)
      afr[mi] = *(const bf16x8*)&ac[lhi * 1024 + (wm * 64 + mi * 16 + l15) * 8];
#pragma unroll
    for (int ni = 0; ni < 4; ++ni)
      bfr[ni] = *(const bf16x8*)&bc[lhi * 1024 + (wn * 64 + ni * 16 + l15) * 8];
    __builtin_amdgcn_s_setprio(1);
#pragma unroll
    for (int mi = 0; mi < 4; ++mi)
#pragma unroll
      for (int ni = 0; ni < 4; ++ni)
        acc[mi][ni] = __builtin_amdgcn_mfma_f32_16x16x32_bf16(afr[mi], bfr[ni], acc[mi][ni], 0, 0, 0);
    __builtin_amdgcn_s_setprio(0);
    ROT3(ac, an, af_);
    ROT3(bc, bn, bf_);
  }
#undef STAGE_G
  float bb[4];
#pragma unroll
  for (int ni = 0; ni < 4; ++ni) bb[ni] = bias[n0 + wn * 64 + ni * 16 + l15];
#pragma unroll
  for (int mi = 0; mi < 4; ++mi)
#pragma unroll
    for (int r = 0; r < 4; ++r) {
      int gm = m0 + wm * 64 + mi * 16 + lhi * 4 + r;
      float* op = outf + (size_t)gm * 1024 + n0 + wn * 64 + l15;
#pragma unroll
      for (int ni = 0; ni < 4; ++ni) op[ni * 16] = acc[mi][ni][r] + bb[ni];
    }
}

// ---------------- Sigmoid attention: R4 data path + triple-buffer K/V,
// ONE barrier per kv step, setprio around MFMA clusters. ----------------
// Q-tile 128/block (wave owns 32 rows), KV-tile 64. grid (16, 32) = 512.
__global__ __launch_bounds__(256, 2)
void attn_kernel(const unsigned short* __restrict__ qh,
                 const unsigned short* __restrict__ kh,
                 const unsigned short* __restrict__ vT,
                 unsigned short* __restrict__ x) {
  __shared__ unsigned short Klds[3][4096];      // [slot][kv_row][chunk^swz]
  __shared__ unsigned short Vlds[3][4096];      // [slot][d][chunk^swz]
  __shared__ unsigned short Plds[4 * 32 * 72];  // per-wave [32][72] (144B stride)
  const int t = threadIdx.x, w = t >> 6, l = t & 63, l15 = l & 15, lhi = l >> 4;
  const int qt = blockIdx.x, bh = blockIdx.y, b = bh >> 4;
  const unsigned short* Q = qh + (size_t)bh * SEQ * 64;
  const unsigned short* K = kh + (size_t)bh * SEQ * 64;
  const unsigned short* V = vT + (size_t)bh * 64 * SEQ;
  unsigned short* Pw = &Plds[w * 32 * 72];
  const int qbase = qt * 128 + w * 32;

  bf16x8 qf[2][2];
#pragma unroll
  for (int mi = 0; mi < 2; ++mi)
#pragma unroll
    for (int kb = 0; kb < 2; ++kb)
      qf[mi][kb] = *(const bf16x8*)&Q[(size_t)(qbase + mi * 16 + l15) * 64 + kb * 32 + lhi * 8];

  f32x4 o[2][4] = {};
  const int r0 = t >> 3, c0 = t & 7, r1 = r0 + 32;

  unsigned short *kc = &Klds[0][0], *kn = &Klds[1][0], *kfu = &Klds[2][0];
  unsigned short *vc = &Vlds[0][0], *vn = &Vlds[1][0], *vfu = &Vlds[2][0];

#define STAGE_KV(kp, vp, kv0) do {                                                  \
    gload_lds16(K + (size_t)((kv0) + r0) * 64 + (c0 ^ (r0 & 7)) * 8, (kp) + t * 8); \
    gload_lds16(K + (size_t)((kv0) + r1) * 64 + (c0 ^ (r1 & 7)) * 8, (kp) + (t + 256) * 8); \
    gload_lds16(V + (size_t)r0 * SEQ + (kv0) + (c0 ^ (r0 & 7)) * 8, (vp) + t * 8);  \
    gload_lds16(V + (size_t)r1 * SEQ + (kv0) + (c0 ^ (r1 & 7)) * 8, (vp) + (t + 256) * 8); \
  } while (0)

  STAGE_KV(kc, vc, 0);
  for (int kv = 0; kv < 32; ++kv) {
    if (kv + 1 < 32) { STAGE_KV(kn, vn, (kv + 1) * 64); VMCNT(4); }
    else             { VMCNT(0); }
    BAR();                        // cur K/V tile valid for all waves

    // QK^T (Q pre-scaled by -0.125*log2e): s[mi][ni], row=q(lhi*4+r), col=kv(l15)
    f32x4 s[2][4] = {};
    __builtin_amdgcn_s_setprio(1);
#pragma unroll
    for (int ni = 0; ni < 4; ++ni)
#pragma unroll
      for (int kb = 0; kb < 2; ++kb) {
        bf16x8 kf = *(const bf16x8*)&kc[(ni * 16 + l15) * 64 + (((kb * 4 + lhi) ^ (l15 & 7)) * 8)];
        s[0][ni] = __builtin_amdgcn_mfma_f32_16x16x32_bf16(qf[0][kb], kf, s[0][ni], 0, 0, 0);
        s[1][ni] = __builtin_amdgcn_mfma_f32_16x16x32_bf16(qf[1][kb], kf, s[1][ni], 0, 0, 0);
      }
    __builtin_amdgcn_s_setprio(0);

    // sigmoid = rcp(1 + exp2(s~)) -> bf16 -> per-wave LDS (R4-proven path)
#pragma unroll
    for (int mi = 0; mi < 2; ++mi)
#pragma unroll
      for (int ni = 0; ni < 4; ++ni)
#pragma unroll
        for (int r = 0; r < 4; ++r) {
          float p = __builtin_amdgcn_rcpf(1.0f + __builtin_amdgcn_exp2f(s[mi][ni][r]));
          Pw[(mi * 16 + lhi * 4 + r) * 72 + ni * 16 + l15] = f2bf_rh(p);
        }
    DSFENCE();                    // P writes complete before P reads

    // PV : O[32][64] += P[32][64] @ V[64][64]
    __builtin_amdgcn_s_setprio(1);
#pragma unroll
    for (int kq = 0; kq < 2; ++kq) {
      bf16x8 pf0 = *(const bf16x8*)&Pw[l15 * 72 + kq * 32 + lhi * 8];
      bf16x8 pf1 = *(const bf16x8*)&Pw[(16 + l15) * 72 + kq * 32 + lhi * 8];
#pragma unroll
      for (int di = 0; di < 4; ++di) {
        bf16x8 vf = *(const bf16x8*)&vc[(di * 16 + l15) * 64 + (((kq * 4 + lhi) ^ (l15 & 7)) * 8)];
        o[0][di] = __builtin_amdgcn_mfma_f32_16x16x32_bf16(pf0, vf, o[0][di], 0, 0, 0);
        o[1][di] = __builtin_amdgcn_mfma_f32_16x16x32_bf16(pf1, vf, o[1][di], 0, 0, 0);
      }
    }
    __builtin_amdgcn_s_setprio(0);

    ROT3(kc, kn, kfu);
    ROT3(vc, vn, vfu);
  }
#undef STAGE_KV

#pragma unroll
  for (int mi = 0; mi < 2; ++mi)
#pragma unroll
    for (int r = 0; r < 4; ++r) {
      int pos = qbase + mi * 16 + lhi * 4 + r;
      size_t base = ((size_t)b * SEQ + pos) * DIM + (bh & 15) * 64;
#pragma unroll
      for (int di = 0; di < 4; ++di)
        x[base + di * 16 + l15] = f2bf(o[mi][di][r]);
    }
}

// ---------------- launch ----------------
extern "C" void kernel_launch(void* const* d_in, const int* in_sizes, int n_in,
                              void* d_out, int out_size, void* d_ws, size_t ws_size,
                              hipStream_t stream) {
  (void)in_sizes; (void)n_in; (void)out_size; (void)ws_size;
  const float* q  = (const float*)d_in[0];
  const float* k  = (const float*)d_in[1];
  const float* v  = (const float*)d_in[2];
  const float* Wq = (const float*)d_in[3];
  const float* Wk = (const float*)d_in[4];
  const float* Wv = (const float*)d_in[5];
  const float* gq = (const float*)d_in[6];
  const float* bq = (const float*)d_in[7];
  const float* gk = (const float*)d_in[8];
  const float* bk = (const float*)d_in[9];
  const float* Wo = (const float*)d_in[10];
  const float* bo = (const float*)d_in[11];
  float* out = (float*)d_out;

  char* ws = (char*)d_ws;
  const size_t MB = 1ull << 20;
  unsigned short* qb  = (unsigned short*)(ws + 0);        // 8MB, reused as x after attn
  unsigned short* kb  = (unsigned short*)(ws + 8  * MB);
  unsigned short* vb  = (unsigned short*)(ws + 16 * MB);
  unsigned short* Wqb = (unsigned short*)(ws + 24 * MB);
  unsigned short* Wkb = (unsigned short*)(ws + 26 * MB);
  unsigned short* Wvb = (unsigned short*)(ws + 28 * MB);
  unsigned short* Wob = (unsigned short*)(ws + 30 * MB);
  unsigned short* qhb = (unsigned short*)(ws + 32 * MB);  // [BH][L][64]
  unsigned short* khb = (unsigned short*)(ws + 40 * MB);  // [BH][L][64]
  unsigned short* vTb = (unsigned short*)(ws + 48 * MB);  // [BH][64][L]
  unsigned short* xb  = qb;

  const int nIn = MTOT * DIM;
  const int nW  = DIM * DIM;

  cvt_f32_bf16<<<dim3(nIn / 1024, 3), 256, 0, stream>>>(q, qb, k, kb, v, vb, nullptr, nullptr, nIn);
  cvt_f32_bf16<<<dim3(nW / 1024, 4), 256, 0, stream>>>(Wq, Wqb, Wk, Wkb, Wv, Wvb, Wo, Wob, nW);

  gemm_qkv<<<dim3(MTOT / 128, DIM / 128, 3), 256, 0, stream>>>(qb, kb, vb, Wqb, Wkb, Wvb,
                                                               gq, bq, gk, bk, qhb, khb, vTb);

  attn_kernel<<<dim3(SEQ / 128, BATCH * NH), 256, 0, stream>>>(qhb, khb, vTb, xb);

  gemm_out<<<dim3(MTOT / 128, DIM / 128), 256, 0, stream>>>(xb, Wob, bo, out);
}

// Round 8
// 158.756 us; speedup vs baseline: 2.0960x; 1.0047x over previous
//
#include <hip/hip_runtime.h>
#include <stdint.h>

// B=2, L=2048, DIM=1024, 16 heads x 64
#define BATCH 2
#define SEQ   2048
#define DIM   1024
#define NH    16
#define MTOT  (BATCH*SEQ)   // 4096
#define LN_EPS 1e-5f
// Q scale folded with -log2(e): sigmoid(s) = rcp(1 + exp2(s*-log2e))
#define Q_FOLD_SCALE (-0.1803368801111204f)   // 0.125 * -1.4426950408889634

typedef __bf16 bf16x8 __attribute__((ext_vector_type(8)));
typedef float  f32x4  __attribute__((ext_vector_type(4)));

__device__ __forceinline__ unsigned short f2bf(float f) {
  uint32_t u = __float_as_uint(f);
  u += 0x7fffu + ((u >> 16) & 1u);      // RNE
  return (unsigned short)(u >> 16);
}
__device__ __forceinline__ unsigned short f2bf_rh(float f) {  // round-half-up (P>=0)
  uint32_t u = __float_as_uint(f) + 0x8000u;
  return (unsigned short)(u >> 16);
}

__device__ __forceinline__ void gload_lds16(const void* g, void* lds) {
  __builtin_amdgcn_global_load_lds(
      (const __attribute__((address_space(1))) uint32_t*)g,
      (__attribute__((address_space(3))) uint32_t*)lds, 16, 0, 0);
}

#define VMCNT(n) asm volatile("s_waitcnt vmcnt(" #n ")" ::: "memory")
#define BAR() do { __builtin_amdgcn_s_barrier(); __builtin_amdgcn_sched_barrier(0); } while (0)
// Fence between LDS writes and subsequent LDS reads of the same buffer (TBAA-
// distinct types on Plds have no alias edge; block compile-time motion + wait).
#define DSFENCE() do {                                        \
    __builtin_amdgcn_sched_barrier(0);                        \
    asm volatile("s_waitcnt lgkmcnt(0)" ::: "memory");        \
    __builtin_amdgcn_sched_barrier(0);                        \
  } while (0)
#define ROT3(a, b, c) do { unsigned short* _tmp = (a); (a) = (b); (b) = (c); (c) = _tmp; } while (0)

// ---------------- f32 -> bf16 conversion ----------------
__global__ void cvt_f32_bf16(const float* __restrict__ s0, unsigned short* __restrict__ d0,
                             const float* __restrict__ s1, unsigned short* __restrict__ d1,
                             const float* __restrict__ s2, unsigned short* __restrict__ d2,
                             const float* __restrict__ s3, unsigned short* __restrict__ d3,
                             int n) {
  int z = blockIdx.y;
  const float* s = z == 0 ? s0 : z == 1 ? s1 : z == 2 ? s2 : s3;
  unsigned short* d = z == 0 ? d0 : z == 1 ? d1 : z == 2 ? d2 : d3;
  if (s == nullptr) return;
  int i = (blockIdx.x * 256 + threadIdx.x) * 4;
  if (i >= n) return;
  float4 v = *(const float4*)(s + i);
  ushort4 o;
  o.x = f2bf(v.x); o.y = f2bf(v.y); o.z = f2bf(v.z); o.w = f2bf(v.w);
  *(ushort4*)(d + i) = o;
}

// ---------------- fused QKV projections: depth-2 prefetch, 3 slots ----------
// C[4096][1024] = A @ W^T. BM=BN=128, BK=32, 4 waves (2x2), wave tile 64x64.
// Step t: stage tile t+2, vmcnt(8) (4 loads/stage => tile t landed), B1,
// compute tile t, B2 (B2 makes re-stage of slot t%3 at step t+1 WAR-safe).
__global__ __launch_bounds__(256, 3)
void gemm_qkv(const unsigned short* __restrict__ Aq, const unsigned short* __restrict__ Ak,
              const unsigned short* __restrict__ Av,
              const unsigned short* __restrict__ Wqp, const unsigned short* __restrict__ Wkp,
              const unsigned short* __restrict__ Wvp,
              const float* __restrict__ gq, const float* __restrict__ bq,
              const float* __restrict__ gk, const float* __restrict__ bk,
              unsigned short* __restrict__ qh, unsigned short* __restrict__ kh,
              unsigned short* __restrict__ vT) {
  __shared__ unsigned short Asm[3][4096];  // [slot][kb4][128][8] 8KB each
  __shared__ unsigned short Bsm[3][4096];
  const int z = blockIdx.z;
  const unsigned short* A = z == 0 ? Aq : z == 1 ? Ak : Av;
  const unsigned short* W = z == 0 ? Wqp : z == 1 ? Wkp : Wvp;
  const int t = threadIdx.x, w = t >> 6, l = t & 63, l15 = l & 15, lhi = l >> 4;
  const int wm = w >> 1, wn = w & 1;
  const int m0 = blockIdx.x * 128, n0 = blockIdx.y * 128;
  const int ldrow = t & 127, ldkb = t >> 7;

  unsigned short *ac = &Asm[0][0], *an = &Asm[1][0], *af_ = &Asm[2][0];
  unsigned short *bc = &Bsm[0][0], *bn = &Bsm[1][0], *bf_ = &Bsm[2][0];

  f32x4 acc[4][4] = {};

#define STAGE_G(ap, bp, kt) do {                                                  \
    int k0 = (kt) * 32;                                                           \
    gload_lds16(A + (size_t)(m0 + ldrow) * 1024 + k0 + ldkb * 8, (ap) + t * 8);   \
    gload_lds16(A + (size_t)(m0 + ldrow) * 1024 + k0 + (ldkb + 2) * 8,            \
                (ap) + (t + 256) * 8);                                            \
    gload_lds16(W + (size_t)(n0 + ldrow) * 1024 + k0 + ldkb * 8, (bp) + t * 8);   \
    gload_lds16(W + (size_t)(n0 + ldrow) * 1024 + k0 + (ldkb + 2) * 8,            \
                (bp) + (t + 256) * 8);                                            \
  } while (0)

  STAGE_G(ac, bc, 0);
  STAGE_G(an, bn, 1);
  for (int kt = 0; kt < 32; ++kt) {
    if (kt < 30)       { STAGE_G(af_, bf_, kt + 2); VMCNT(8); }
    else if (kt == 30) { VMCNT(4); }
    else               { VMCNT(0); }
    BAR();                       // cur tile landed for ALL waves
    bf16x8 afr[4], bfr[4];
#pragma unroll
    for (int mi = 0; mi < 4; ++mi)
      afr[mi] = *(const bf16x8*)&ac[lhi * 1024 + (wm * 64 + mi * 16 + l15) * 8];
#pragma unroll
    for (int ni = 0; ni < 4; ++ni)
      bfr[ni] = *(const bf16x8*)&bc[lhi * 1024 + (wn * 64 + ni * 16 + l15) * 8];
    __builtin_amdgcn_s_setprio(1);
#pragma unroll
    for (int mi = 0; mi < 4; ++mi)
#pragma unroll
      for (int ni = 0; ni < 4; ++ni)
        acc[mi][ni] = __builtin_amdgcn_mfma_f32_16x16x32_bf16(afr[mi], bfr[ni], acc[mi][ni], 0, 0, 0);
    __builtin_amdgcn_s_setprio(0);
    BAR();                       // readers done before slot re-stage next step
    ROT3(ac, an, af_);
    ROT3(bc, bn, bf_);
  }
#undef STAGE_G

  const int h = (n0 >> 6) + wn;
  if (z == 2) {
#pragma unroll
    for (int mi = 0; mi < 4; ++mi)
#pragma unroll
      for (int r = 0; r < 4; ++r) {
        int gm = m0 + wm * 64 + mi * 16 + lhi * 4 + r;
        int b = gm >> 11, pos = gm & 2047;
#pragma unroll
        for (int ni = 0; ni < 4; ++ni)
          vT[(((size_t)(b * NH + h)) * 64 + ni * 16 + l15) * SEQ + pos] = f2bf(acc[mi][ni][r]);
      }
  } else {
    const float* G  = z ? gk : gq;
    const float* Bt = z ? bk : bq;
    unsigned short* outp = z ? kh : qh;
    const float sc = z ? 1.f : Q_FOLD_SCALE;
    float g[4], bt[4];
#pragma unroll
    for (int ni = 0; ni < 4; ++ni) { g[ni] = G[ni * 16 + l15]; bt[ni] = Bt[ni * 16 + l15]; }
#pragma unroll
    for (int mi = 0; mi < 4; ++mi)
#pragma unroll
      for (int r = 0; r < 4; ++r) {
        float x[4], s = 0.f, s2 = 0.f;
#pragma unroll
        for (int ni = 0; ni < 4; ++ni) { x[ni] = acc[mi][ni][r]; s += x[ni]; s2 += x[ni] * x[ni]; }
#pragma unroll
        for (int msk = 1; msk < 16; msk <<= 1) {
          s  += __shfl_xor(s,  msk, 64);
          s2 += __shfl_xor(s2, msk, 64);
        }
        float mu = s * (1.f / 64.f);
        float var = s2 * (1.f / 64.f) - mu * mu;
        float rstd = rsqrtf(var + LN_EPS);
        int gm = m0 + wm * 64 + mi * 16 + lhi * 4 + r;
        int b = gm >> 11, pos = gm & 2047;
        size_t base = (((size_t)(b * NH + h)) * SEQ + pos) * 64;
#pragma unroll
        for (int ni = 0; ni < 4; ++ni) {
          float y = ((x[ni] - mu) * rstd * g[ni] + bt[ni]) * sc;
          outp[base + ni * 16 + l15] = f2bf(y);
        }
      }
  }
}

// ---------------- out projection: out = x @ Wo^T + bo (f32), depth-2 ---------
__global__ __launch_bounds__(256, 3)
void gemm_out(const unsigned short* __restrict__ A, const unsigned short* __restrict__ W,
              const float* __restrict__ bias, float* __restrict__ outf) {
  __shared__ unsigned short Asm[3][4096];
  __shared__ unsigned short Bsm[3][4096];
  const int t = threadIdx.x, w = t >> 6, l = t & 63, l15 = l & 15, lhi = l >> 4;
  const int wm = w >> 1, wn = w & 1;
  const int m0 = blockIdx.x * 128, n0 = blockIdx.y * 128;
  const int ldrow = t & 127, ldkb = t >> 7;

  unsigned short *ac = &Asm[0][0], *an = &Asm[1][0], *af_ = &Asm[2][0];
  unsigned short *bc = &Bsm[0][0], *bn = &Bsm[1][0], *bf_ = &Bsm[2][0];
  f32x4 acc[4][4] = {};

#define STAGE_G(ap, bp, kt) do {                                                  \
    int k0 = (kt) * 32;                                                           \
    gload_lds16(A + (size_t)(m0 + ldrow) * 1024 + k0 + ldkb * 8, (ap) + t * 8);   \
    gload_lds16(A + (size_t)(m0 + ldrow) * 1024 + k0 + (ldkb + 2) * 8,            \
                (ap) + (t + 256) * 8);                                            \
    gload_lds16(W + (size_t)(n0 + ldrow) * 1024 + k0 + ldkb * 8, (bp) + t * 8);   \
    gload_lds16(W + (size_t)(n0 + ldrow) * 1024 + k0 + (ldkb + 2) * 8,            \
                (bp) + (t + 256) * 8);                                            \
  } while (0)

  STAGE_G(ac, bc, 0);
  STAGE_G(an, bn, 1);
  for (int kt = 0; kt < 32; ++kt) {
    if (kt < 30)       { STAGE_G(af_, bf_, kt + 2); VMCNT(8); }
    else if (kt == 30) { VMCNT(4); }
    else               { VMCNT(0); }
    BAR();
    bf16x8 afr[4], bfr[4];
#pragma unroll
    for (int mi = 0; mi < 4; ++mi)
      afr[mi] = *(const bf16x8*)&ac[lhi * 1024 + (wm * 64 + mi * 16 + l15) * 8];
#pragma unroll
    for (int ni = 0; ni < 4; ++ni)
      bfr[ni] = *(const bf16x8*)&bc[lhi * 1024 + (wn * 64 + ni * 16 + l15) * 8];
    __builtin_amdgcn_s_setprio(1);
#pragma unroll
    for (int mi = 0; mi < 4; ++mi)
#pragma unroll
      for (int ni = 0; ni < 4; ++ni)
        acc[mi][ni] = __builtin_amdgcn_mfma_f32_16x16x32_bf16(afr[mi], bfr[ni], acc[mi][ni], 0, 0, 0);
    __builtin_amdgcn_s_setprio(0);
    BAR();
    ROT3(ac, an, af_);
    ROT3(bc, bn, bf_);
  }
#undef STAGE_G
  float bb[4];
#pragma unroll
  for (int ni = 0; ni < 4; ++ni) bb[ni] = bias[n0 + wn * 64 + ni * 16 + l15];
#pragma unroll
  for (int mi = 0; mi < 4; ++mi)
#pragma unroll
    for (int r = 0; r < 4; ++r) {
      int gm = m0 + wm * 64 + mi * 16 + lhi * 4 + r;
      float* op = outf + (size_t)gm * 1024 + n0 + wn * 64 + l15;
#pragma unroll
      for (int ni = 0; ni < 4; ++ni) op[ni * 16] = acc[mi][ni][r] + bb[ni];
    }
}

// ---------------- Sigmoid attention: depth-2 prefetch + XCD head-chunking ----
// Q-tile 128/block (wave owns 32 rows), KV-tile 64, 3 K/V slots, 2 barriers.
// 1-D grid 512; L%8 = XCD -> each XCD owns 4 heads (2MB K/V, L2-resident).
__global__ __launch_bounds__(256, 2)
void attn_kernel(const unsigned short* __restrict__ qh,
                 const unsigned short* __restrict__ kh,
                 const unsigned short* __restrict__ vT,
                 unsigned short* __restrict__ x) {
  __shared__ unsigned short Klds[3][4096];      // [slot][kv_row][chunk^swz]
  __shared__ unsigned short Vlds[3][4096];      // [slot][d][chunk^swz]
  __shared__ unsigned short Plds[4 * 32 * 72];  // per-wave [32][72] (144B stride)
  const int t = threadIdx.x, w = t >> 6, l = t & 63, l15 = l & 15, lhi = l >> 4;
  const int L = blockIdx.x;
  const int xcd = L & 7, j = L >> 3;
  const int bh = xcd * 4 + (j >> 4);   // 4 heads per XCD
  const int qt = j & 15;
  const int b = bh >> 4;
  const unsigned short* Q = qh + (size_t)bh * SEQ * 64;
  const unsigned short* K = kh + (size_t)bh * SEQ * 64;
  const unsigned short* V = vT + (size_t)bh * 64 * SEQ;
  unsigned short* Pw = &Plds[w * 32 * 72];
  const int qbase = qt * 128 + w * 32;

  bf16x8 qf[2][2];
#pragma unroll
  for (int mi = 0; mi < 2; ++mi)
#pragma unroll
    for (int kb = 0; kb < 2; ++kb)
      qf[mi][kb] = *(const bf16x8*)&Q[(size_t)(qbase + mi * 16 + l15) * 64 + kb * 32 + lhi * 8];

  f32x4 o[2][4] = {};
  const int r0 = t >> 3, c0 = t & 7, r1 = r0 + 32;

  unsigned short *kc = &Klds[0][0], *kn = &Klds[1][0], *kfu = &Klds[2][0];
  unsigned short *vc = &Vlds[0][0], *vn = &Vlds[1][0], *vfu = &Vlds[2][0];

#define STAGE_KV(kp, vp, kv0) do {                                                  \
    gload_lds16(K + (size_t)((kv0) + r0) * 64 + (c0 ^ (r0 & 7)) * 8, (kp) + t * 8); \
    gload_lds16(K + (size_t)((kv0) + r1) * 64 + (c0 ^ (r1 & 7)) * 8, (kp) + (t + 256) * 8); \
    gload_lds16(V + (size_t)r0 * SEQ + (kv0) + (c0 ^ (r0 & 7)) * 8, (vp) + t * 8);  \
    gload_lds16(V + (size_t)r1 * SEQ + (kv0) + (c0 ^ (r1 & 7)) * 8, (vp) + (t + 256) * 8); \
  } while (0)

  STAGE_KV(kc, vc, 0);
  STAGE_KV(kn, vn, 64);
  for (int kv = 0; kv < 32; ++kv) {
    if (kv < 30)       { STAGE_KV(kfu, vfu, (kv + 2) * 64); VMCNT(8); }
    else if (kv == 30) { VMCNT(4); }
    else               { VMCNT(0); }
    BAR();                        // cur K/V tile valid for all waves

    // QK^T (Q pre-scaled by -0.125*log2e): s[mi][ni], row=q(lhi*4+r), col=kv(l15)
    f32x4 s[2][4] = {};
    __builtin_amdgcn_s_setprio(1);
#pragma unroll
    for (int ni = 0; ni < 4; ++ni)
#pragma unroll
      for (int kb = 0; kb < 2; ++kb) {
        bf16x8 kf = *(const bf16x8*)&kc[(ni * 16 + l15) * 64 + (((kb * 4 + lhi) ^ (l15 & 7)) * 8)];
        s[0][ni] = __builtin_amdgcn_mfma_f32_16x16x32_bf16(qf[0][kb], kf, s[0][ni], 0, 0, 0);
        s[1][ni] = __builtin_amdgcn_mfma_f32_16x16x32_bf16(qf[1][kb], kf, s[1][ni], 0, 0, 0);
      }
    __builtin_amdgcn_s_setprio(0);

    // sigmoid = rcp(1 + exp2(s~)) -> bf16 -> per-wave LDS
#pragma unroll
    for (int mi = 0; mi < 2; ++mi)
#pragma unroll
      for (int ni = 0; ni < 4; ++ni)
#pragma unroll
        for (int r = 0; r < 4; ++r) {
          float p = __builtin_amdgcn_rcpf(1.0f + __builtin_amdgcn_exp2f(s[mi][ni][r]));
          Pw[(mi * 16 + lhi * 4 + r) * 72 + ni * 16 + l15] = f2bf_rh(p);
        }
    DSFENCE();                    // P writes complete before P reads

    // PV : O[32][64] += P[32][64] @ V[64][64]
    __builtin_amdgcn_s_setprio(1);
#pragma unroll
    for (int kq = 0; kq < 2; ++kq) {
      bf16x8 pf0 = *(const bf16x8*)&Pw[l15 * 72 + kq * 32 + lhi * 8];
      bf16x8 pf1 = *(const bf16x8*)&Pw[(16 + l15) * 72 + kq * 32 + lhi * 8];
#pragma unroll
      for (int di = 0; di < 4; ++di) {
        bf16x8 vf = *(const bf16x8*)&vc[(di * 16 + l15) * 64 + (((kq * 4 + lhi) ^ (l15 & 7)) * 8)];
        o[0][di] = __builtin_amdgcn_mfma_f32_16x16x32_bf16(pf0, vf, o[0][di], 0, 0, 0);
        o[1][di] = __builtin_amdgcn_mfma_f32_16x16x32_bf16(pf1, vf, o[1][di], 0, 0, 0);
      }
    }
    __builtin_amdgcn_s_setprio(0);
    BAR();                        // readers done before slot re-stage next step

    ROT3(kc, kn, kfu);
    ROT3(vc, vn, vfu);
  }
#undef STAGE_KV

#pragma unroll
  for (int mi = 0; mi < 2; ++mi)
#pragma unroll
    for (int r = 0; r < 4; ++r) {
      int pos = qbase + mi * 16 + lhi * 4 + r;
      size_t base = ((size_t)b * SEQ + pos) * DIM + (bh & 15) * 64;
#pragma unroll
      for (int di = 0; di < 4; ++di)
        x[base + di * 16 + l15] = f2bf(o[mi][di][r]);
    }
}

// ---------------- launch ----------------
extern "C" void kernel_launch(void* const* d_in, const int* in_sizes, int n_in,
                              void* d_out, int out_size, void* d_ws, size_t ws_size,
                              hipStream_t stream) {
  (void)in_sizes; (void)n_in; (void)out_size; (void)ws_size;
  const float* q  = (const float*)d_in[0];
  const float* k  = (const float*)d_in[1];
  const float* v  = (const float*)d_in[2];
  const float* Wq = (const float*)d_in[3];
  const float* Wk = (const float*)d_in[4];
  const float* Wv = (const float*)d_in[5];
  const float* gq = (const float*)d_in[6];
  const float* bq = (const float*)d_in[7];
  const float* gk = (const float*)d_in[8];
  const float* bk = (const float*)d_in[9];
  const float* Wo = (const float*)d_in[10];
  const float* bo = (const float*)d_in[11];
  float* out = (float*)d_out;

  char* ws = (char*)d_ws;
  const size_t MB = 1ull << 20;
  unsigned short* qb  = (unsigned short*)(ws + 0);        // 8MB, reused as x after attn
  unsigned short* kb  = (unsigned short*)(ws + 8  * MB);
  unsigned short* vb  = (unsigned short*)(ws + 16 * MB);
  unsigned short* Wqb = (unsigned short*)(ws + 24 * MB);
  unsigned short* Wkb = (unsigned short*)(ws + 26 * MB);
  unsigned short* Wvb = (unsigned short*)(ws + 28 * MB);
  unsigned short* Wob = (unsigned short*)(ws + 30 * MB);
  unsigned short* qhb = (unsigned short*)(ws + 32 * MB);  // [BH][L][64]
  unsigned short* khb = (unsigned short*)(ws + 40 * MB);  // [BH][L][64]
  unsigned short* vTb = (unsigned short*)(ws + 48 * MB);  // [BH][64][L]
  unsigned short* xb  = qb;

  const int nIn = MTOT * DIM;
  const int nW  = DIM * DIM;

  cvt_f32_bf16<<<dim3(nIn / 1024, 3), 256, 0, stream>>>(q, qb, k, kb, v, vb, nullptr, nullptr, nIn);
  cvt_f32_bf16<<<dim3(nW / 1024, 4), 256, 0, stream>>>(Wq, Wqb, Wk, Wkb, Wv, Wvb, Wo, Wob, nW);

  gemm_qkv<<<dim3(MTOT / 128, DIM / 128, 3), 256, 0, stream>>>(qb, kb, vb, Wqb, Wkb, Wvb,
                                                               gq, bq, gk, bk, qhb, khb, vTb);

  attn_kernel<<<dim3(512), 256, 0, stream>>>(qhb, khb, vTb, xb);

  gemm_out<<<dim3(MTOT / 128, DIM / 128), 256, 0, stream>>>(xb, Wob, bo, out);
}

// Round 9
// 155.765 us; speedup vs baseline: 2.1363x; 1.0192x over previous
//
#include <hip/hip_runtime.h>
#include <stdint.h>

// B=2, L=2048, DIM=1024, 16 heads x 64
#define BATCH 2
#define SEQ   2048
#define DIM   1024
#define NH    16
#define MTOT  (BATCH*SEQ)   // 4096
#define LN_EPS 1e-5f
// Q scale folded with -log2(e): sigmoid(s) = rcp(1 + exp2(s*-log2e))
#define Q_FOLD_SCALE (-0.1803368801111204f)   // 0.125 * -1.4426950408889634

typedef __bf16 bf16x8 __attribute__((ext_vector_type(8)));
typedef float  f32x4  __attribute__((ext_vector_type(4)));

__device__ __forceinline__ unsigned short f2bf(float f) {
  uint32_t u = __float_as_uint(f);
  u += 0x7fffu + ((u >> 16) & 1u);      // RNE
  return (unsigned short)(u >> 16);
}
__device__ __forceinline__ unsigned short f2bf_rh(float f) {  // round-half-up (P>=0)
  uint32_t u = __float_as_uint(f) + 0x8000u;
  return (unsigned short)(u >> 16);
}

__device__ __forceinline__ void gload_lds16(const void* g, void* lds) {
  __builtin_amdgcn_global_load_lds(
      (const __attribute__((address_space(1))) uint32_t*)g,
      (__attribute__((address_space(3))) uint32_t*)lds, 16, 0, 0);
}

#define VMCNT(n) asm volatile("s_waitcnt vmcnt(" #n ")" ::: "memory")
#define BAR() do { __builtin_amdgcn_s_barrier(); __builtin_amdgcn_sched_barrier(0); } while (0)
// Fence between LDS writes and subsequent LDS reads of the same buffer (TBAA-
// distinct types on Plds have no alias edge; block compile-time motion + wait).
#define DSFENCE() do {                                        \
    __builtin_amdgcn_sched_barrier(0);                        \
    asm volatile("s_waitcnt lgkmcnt(0)" ::: "memory");        \
    __builtin_amdgcn_sched_barrier(0);                        \
  } while (0)
#define ROT3(a, b, c) do { unsigned short* _tmp = (a); (a) = (b); (b) = (c); (c) = _tmp; } while (0)

// ---------------- f32 -> bf16 conversion ----------------
__global__ void cvt_f32_bf16(const float* __restrict__ s0, unsigned short* __restrict__ d0,
                             const float* __restrict__ s1, unsigned short* __restrict__ d1,
                             const float* __restrict__ s2, unsigned short* __restrict__ d2,
                             const float* __restrict__ s3, unsigned short* __restrict__ d3,
                             int n) {
  int z = blockIdx.y;
  const float* s = z == 0 ? s0 : z == 1 ? s1 : z == 2 ? s2 : s3;
  unsigned short* d = z == 0 ? d0 : z == 1 ? d1 : z == 2 ? d2 : d3;
  if (s == nullptr) return;
  int i = (blockIdx.x * 256 + threadIdx.x) * 4;
  if (i >= n) return;
  float4 v = *(const float4*)(s + i);
  ushort4 o;
  o.x = f2bf(v.x); o.y = f2bf(v.y); o.z = f2bf(v.z); o.w = f2bf(v.w);
  *(ushort4*)(d + i) = o;
}

// ---------------- fused QKV projections: depth-2 prefetch, 3 slots ----------
__global__ __launch_bounds__(256, 3)
void gemm_qkv(const unsigned short* __restrict__ Aq, const unsigned short* __restrict__ Ak,
              const unsigned short* __restrict__ Av,
              const unsigned short* __restrict__ Wqp, const unsigned short* __restrict__ Wkp,
              const unsigned short* __restrict__ Wvp,
              const float* __restrict__ gq, const float* __restrict__ bq,
              const float* __restrict__ gk, const float* __restrict__ bk,
              unsigned short* __restrict__ qh, unsigned short* __restrict__ kh,
              unsigned short* __restrict__ vT) {
  __shared__ unsigned short Asm[3][4096];  // [slot][kb4][128][8] 8KB each
  __shared__ unsigned short Bsm[3][4096];
  const int z = blockIdx.z;
  const unsigned short* A = z == 0 ? Aq : z == 1 ? Ak : Av;
  const unsigned short* W = z == 0 ? Wqp : z == 1 ? Wkp : Wvp;
  const int t = threadIdx.x, w = t >> 6, l = t & 63, l15 = l & 15, lhi = l >> 4;
  const int wm = w >> 1, wn = w & 1;
  const int m0 = blockIdx.x * 128, n0 = blockIdx.y * 128;
  const int ldrow = t & 127, ldkb = t >> 7;

  unsigned short *ac = &Asm[0][0], *an = &Asm[1][0], *af_ = &Asm[2][0];
  unsigned short *bc = &Bsm[0][0], *bn = &Bsm[1][0], *bf_ = &Bsm[2][0];

  f32x4 acc[4][4] = {};

#define STAGE_G(ap, bp, kt) do {                                                  \
    int k0 = (kt) * 32;                                                           \
    gload_lds16(A + (size_t)(m0 + ldrow) * 1024 + k0 + ldkb * 8, (ap) + t * 8);   \
    gload_lds16(A + (size_t)(m0 + ldrow) * 1024 + k0 + (ldkb + 2) * 8,            \
                (ap) + (t + 256) * 8);                                            \
    gload_lds16(W + (size_t)(n0 + ldrow) * 1024 + k0 + ldkb * 8, (bp) + t * 8);   \
    gload_lds16(W + (size_t)(n0 + ldrow) * 1024 + k0 + (ldkb + 2) * 8,            \
                (bp) + (t + 256) * 8);                                            \
  } while (0)

  STAGE_G(ac, bc, 0);
  STAGE_G(an, bn, 1);
  for (int kt = 0; kt < 32; ++kt) {
    if (kt < 30)       { STAGE_G(af_, bf_, kt + 2); VMCNT(8); }
    else if (kt == 30) { VMCNT(4); }
    else               { VMCNT(0); }
    BAR();                       // cur tile landed for ALL waves
    bf16x8 afr[4], bfr[4];
#pragma unroll
    for (int mi = 0; mi < 4; ++mi)
      afr[mi] = *(const bf16x8*)&ac[lhi * 1024 + (wm * 64 + mi * 16 + l15) * 8];
#pragma unroll
    for (int ni = 0; ni < 4; ++ni)
      bfr[ni] = *(const bf16x8*)&bc[lhi * 1024 + (wn * 64 + ni * 16 + l15) * 8];
    __builtin_amdgcn_s_setprio(1);
#pragma unroll
    for (int mi = 0; mi < 4; ++mi)
#pragma unroll
      for (int ni = 0; ni < 4; ++ni)
        acc[mi][ni] = __builtin_amdgcn_mfma_f32_16x16x32_bf16(afr[mi], bfr[ni], acc[mi][ni], 0, 0, 0);
    __builtin_amdgcn_s_setprio(0);
    BAR();                       // readers done before slot re-stage next step
    ROT3(ac, an, af_);
    ROT3(bc, bn, bf_);
  }
#undef STAGE_G

  const int h = (n0 >> 6) + wn;
  if (z == 2) {
#pragma unroll
    for (int mi = 0; mi < 4; ++mi)
#pragma unroll
      for (int r = 0; r < 4; ++r) {
        int gm = m0 + wm * 64 + mi * 16 + lhi * 4 + r;
        int b = gm >> 11, pos = gm & 2047;
#pragma unroll
        for (int ni = 0; ni < 4; ++ni)
          vT[(((size_t)(b * NH + h)) * 64 + ni * 16 + l15) * SEQ + pos] = f2bf(acc[mi][ni][r]);
      }
  } else {
    const float* G  = z ? gk : gq;
    const float* Bt = z ? bk : bq;
    unsigned short* outp = z ? kh : qh;
    const float sc = z ? 1.f : Q_FOLD_SCALE;
    float g[4], bt[4];
#pragma unroll
    for (int ni = 0; ni < 4; ++ni) { g[ni] = G[ni * 16 + l15]; bt[ni] = Bt[ni * 16 + l15]; }
#pragma unroll
    for (int mi = 0; mi < 4; ++mi)
#pragma unroll
      for (int r = 0; r < 4; ++r) {
        float x[4], s = 0.f, s2 = 0.f;
#pragma unroll
        for (int ni = 0; ni < 4; ++ni) { x[ni] = acc[mi][ni][r]; s += x[ni]; s2 += x[ni] * x[ni]; }
#pragma unroll
        for (int msk = 1; msk < 16; msk <<= 1) {
          s  += __shfl_xor(s,  msk, 64);
          s2 += __shfl_xor(s2, msk, 64);
        }
        float mu = s * (1.f / 64.f);
        float var = s2 * (1.f / 64.f) - mu * mu;
        float rstd = rsqrtf(var + LN_EPS);
        int gm = m0 + wm * 64 + mi * 16 + lhi * 4 + r;
        int b = gm >> 11, pos = gm & 2047;
        size_t base = (((size_t)(b * NH + h)) * SEQ + pos) * 64;
#pragma unroll
        for (int ni = 0; ni < 4; ++ni) {
          float y = ((x[ni] - mu) * rstd * g[ni] + bt[ni]) * sc;
          outp[base + ni * 16 + l15] = f2bf(y);
        }
      }
  }
}

// ---------------- out projection: out = x @ Wo^T + bo (f32), depth-2 ---------
__global__ __launch_bounds__(256, 3)
void gemm_out(const unsigned short* __restrict__ A, const unsigned short* __restrict__ W,
              const float* __restrict__ bias, float* __restrict__ outf) {
  __shared__ unsigned short Asm[3][4096];
  __shared__ unsigned short Bsm[3][4096];
  const int t = threadIdx.x, w = t >> 6, l = t & 63, l15 = l & 15, lhi = l >> 4;
  const int wm = w >> 1, wn = w & 1;
  const int m0 = blockIdx.x * 128, n0 = blockIdx.y * 128;
  const int ldrow = t & 127, ldkb = t >> 7;

  unsigned short *ac = &Asm[0][0], *an = &Asm[1][0], *af_ = &Asm[2][0];
  unsigned short *bc = &Bsm[0][0], *bn = &Bsm[1][0], *bf_ = &Bsm[2][0];
  f32x4 acc[4][4] = {};

#define STAGE_G(ap, bp, kt) do {                                                  \
    int k0 = (kt) * 32;                                                           \
    gload_lds16(A + (size_t)(m0 + ldrow) * 1024 + k0 + ldkb * 8, (ap) + t * 8);   \
    gload_lds16(A + (size_t)(m0 + ldrow) * 1024 + k0 + (ldkb + 2) * 8,            \
                (ap) + (t + 256) * 8);                                            \
    gload_lds16(W + (size_t)(n0 + ldrow) * 1024 + k0 + ldkb * 8, (bp) + t * 8);   \
    gload_lds16(W + (size_t)(n0 + ldrow) * 1024 + k0 + (ldkb + 2) * 8,            \
                (bp) + (t + 256) * 8);                                            \
  } while (0)

  STAGE_G(ac, bc, 0);
  STAGE_G(an, bn, 1);
  for (int kt = 0; kt < 32; ++kt) {
    if (kt < 30)       { STAGE_G(af_, bf_, kt + 2); VMCNT(8); }
    else if (kt == 30) { VMCNT(4); }
    else               { VMCNT(0); }
    BAR();
    bf16x8 afr[4], bfr[4];
#pragma unroll
    for (int mi = 0; mi < 4; ++mi)
      afr[mi] = *(const bf16x8*)&ac[lhi * 1024 + (wm * 64 + mi * 16 + l15) * 8];
#pragma unroll
    for (int ni = 0; ni < 4; ++ni)
      bfr[ni] = *(const bf16x8*)&bc[lhi * 1024 + (wn * 64 + ni * 16 + l15) * 8];
    __builtin_amdgcn_s_setprio(1);
#pragma unroll
    for (int mi = 0; mi < 4; ++mi)
#pragma unroll
      for (int ni = 0; ni < 4; ++ni)
        acc[mi][ni] = __builtin_amdgcn_mfma_f32_16x16x32_bf16(afr[mi], bfr[ni], acc[mi][ni], 0, 0, 0);
    __builtin_amdgcn_s_setprio(0);
    BAR();
    ROT3(ac, an, af_);
    ROT3(bc, bn, bf_);
  }
#undef STAGE_G
  float bb[4];
#pragma unroll
  for (int ni = 0; ni < 4; ++ni) bb[ni] = bias[n0 + wn * 64 + ni * 16 + l15];
#pragma unroll
  for (int mi = 0; mi < 4; ++mi)
#pragma unroll
    for (int r = 0; r < 4; ++r) {
      int gm = m0 + wm * 64 + mi * 16 + lhi * 4 + r;
      float* op = outf + (size_t)gm * 1024 + n0 + wn * 64 + l15;
#pragma unroll
      for (int ni = 0; ni < 4; ++ni) op[ni * 16] = acc[mi][ni][r] + bb[ni];
    }
}

// ---------------- Sigmoid attention: 8 waves x 16 q-rows (512 threads) -------
// Same data path as R8; doubled waves/SIMD (2->4) so one wave's sigmoid
// (trans/VALU) overlaps another's MFMA. Depth-2 K/V staging, 3 slots,
// 1 K-load + 1 V-load per thread per step -> vmcnt(4)/(2)/(0).
// 1-D grid 512; L%8 = XCD -> each XCD owns 4 heads (2MB K/V, L2-resident).
__global__ __launch_bounds__(512, 4)
void attn_kernel(const unsigned short* __restrict__ qh,
                 const unsigned short* __restrict__ kh,
                 const unsigned short* __restrict__ vT,
                 unsigned short* __restrict__ x) {
  __shared__ unsigned short Klds[3][4096];      // [slot][kv_row][chunk^swz] 8KB
  __shared__ unsigned short Vlds[3][4096];      // [slot][d][chunk^swz]
  __shared__ unsigned short Plds[8 * 16 * 72];  // per-wave [16][72] (144B stride)
  const int t = threadIdx.x, w = t >> 6, l = t & 63, l15 = l & 15, lhi = l >> 4;
  const int L = blockIdx.x;
  const int xcd = L & 7, j = L >> 3;
  const int bh = xcd * 4 + (j >> 4);   // 4 heads per XCD
  const int qt = j & 15;
  const int b = bh >> 4;
  const unsigned short* Q = qh + (size_t)bh * SEQ * 64;
  const unsigned short* K = kh + (size_t)bh * SEQ * 64;
  const unsigned short* V = vT + (size_t)bh * 64 * SEQ;
  unsigned short* Pw = &Plds[w * 16 * 72];
  const int qbase = qt * 128 + w * 16;

  bf16x8 qf[2];
#pragma unroll
  for (int kb = 0; kb < 2; ++kb)
    qf[kb] = *(const bf16x8*)&Q[(size_t)(qbase + l15) * 64 + kb * 32 + lhi * 8];

  f32x4 o[4] = {};
  const int r0 = t >> 3, c0 = t & 7;   // t in [0,512): r0 covers 0..63

  unsigned short *kc = &Klds[0][0], *kn = &Klds[1][0], *kfu = &Klds[2][0];
  unsigned short *vc = &Vlds[0][0], *vn = &Vlds[1][0], *vfu = &Vlds[2][0];

#define STAGE_KV(kp, vp, kv0) do {                                                  \
    gload_lds16(K + (size_t)((kv0) + r0) * 64 + (c0 ^ (r0 & 7)) * 8, (kp) + t * 8); \
    gload_lds16(V + (size_t)r0 * SEQ + (kv0) + (c0 ^ (r0 & 7)) * 8, (vp) + t * 8);  \
  } while (0)

  STAGE_KV(kc, vc, 0);
  STAGE_KV(kn, vn, 64);
  for (int kv = 0; kv < 32; ++kv) {
    if (kv < 30)       { STAGE_KV(kfu, vfu, (kv + 2) * 64); VMCNT(4); }
    else if (kv == 30) { VMCNT(2); }
    else               { VMCNT(0); }
    BAR();                        // cur K/V tile valid for all waves

    // QK^T (Q pre-scaled by -0.125*log2e): s[ni], row=q(lhi*4+r), col=kv(ni*16+l15)
    f32x4 s[4] = {};
    __builtin_amdgcn_s_setprio(1);
#pragma unroll
    for (int ni = 0; ni < 4; ++ni)
#pragma unroll
      for (int kb = 0; kb < 2; ++kb) {
        bf16x8 kf = *(const bf16x8*)&kc[(ni * 16 + l15) * 64 + (((kb * 4 + lhi) ^ (l15 & 7)) * 8)];
        s[ni] = __builtin_amdgcn_mfma_f32_16x16x32_bf16(qf[kb], kf, s[ni], 0, 0, 0);
      }
    __builtin_amdgcn_s_setprio(0);

    // sigmoid = rcp(1 + exp2(s~)) -> bf16 -> per-wave LDS
#pragma unroll
    for (int ni = 0; ni < 4; ++ni)
#pragma unroll
      for (int r = 0; r < 4; ++r) {
        float p = __builtin_amdgcn_rcpf(1.0f + __builtin_amdgcn_exp2f(s[ni][r]));
        Pw[(lhi * 4 + r) * 72 + ni * 16 + l15] = f2bf_rh(p);
      }
    DSFENCE();                    // P writes complete before P reads

    // PV : O[16][64] += P[16][64] @ V[64][64]
    __builtin_amdgcn_s_setprio(1);
#pragma unroll
    for (int kq = 0; kq < 2; ++kq) {
      bf16x8 pf = *(const bf16x8*)&Pw[l15 * 72 + kq * 32 + lhi * 8];
#pragma unroll
      for (int di = 0; di < 4; ++di) {
        bf16x8 vf = *(const bf16x8*)&vc[(di * 16 + l15) * 64 + (((kq * 4 + lhi) ^ (l15 & 7)) * 8)];
        o[di] = __builtin_amdgcn_mfma_f32_16x16x32_bf16(pf, vf, o[di], 0, 0, 0);
      }
    }
    __builtin_amdgcn_s_setprio(0);
    BAR();                        // readers done before slot re-stage next step

    ROT3(kc, kn, kfu);
    ROT3(vc, vn, vfu);
  }
#undef STAGE_KV

#pragma unroll
  for (int r = 0; r < 4; ++r) {
    int pos = qbase + lhi * 4 + r;
    size_t base = ((size_t)b * SEQ + pos) * DIM + (bh & 15) * 64;
#pragma unroll
    for (int di = 0; di < 4; ++di)
      x[base + di * 16 + l15] = f2bf(o[di][r]);
  }
}

// ---------------- launch ----------------
extern "C" void kernel_launch(void* const* d_in, const int* in_sizes, int n_in,
                              void* d_out, int out_size, void* d_ws, size_t ws_size,
                              hipStream_t stream) {
  (void)in_sizes; (void)n_in; (void)out_size; (void)ws_size;
  const float* q  = (const float*)d_in[0];
  const float* k  = (const float*)d_in[1];
  const float* v  = (const float*)d_in[2];
  const float* Wq = (const float*)d_in[3];
  const float* Wk = (const float*)d_in[4];
  const float* Wv = (const float*)d_in[5];
  const float* gq = (const float*)d_in[6];
  const float* bq = (const float*)d_in[7];
  const float* gk = (const float*)d_in[8];
  const float* bk = (const float*)d_in[9];
  const float* Wo = (const float*)d_in[10];
  const float* bo = (const float*)d_in[11];
  float* out = (float*)d_out;

  char* ws = (char*)d_ws;
  const size_t MB = 1ull << 20;
  unsigned short* qb  = (unsigned short*)(ws + 0);        // 8MB, reused as x after attn
  unsigned short* kb  = (unsigned short*)(ws + 8  * MB);
  unsigned short* vb  = (unsigned short*)(ws + 16 * MB);
  unsigned short* Wqb = (unsigned short*)(ws + 24 * MB);
  unsigned short* Wkb = (unsigned short*)(ws + 26 * MB);
  unsigned short* Wvb = (unsigned short*)(ws + 28 * MB);
  unsigned short* Wob = (unsigned short*)(ws + 30 * MB);
  unsigned short* qhb = (unsigned short*)(ws + 32 * MB);  // [BH][L][64]
  unsigned short* khb = (unsigned short*)(ws + 40 * MB);  // [BH][L][64]
  unsigned short* vTb = (unsigned short*)(ws + 48 * MB);  // [BH][64][L]
  unsigned short* xb  = qb;

  const int nIn = MTOT * DIM;
  const int nW  = DIM * DIM;

  cvt_f32_bf16<<<dim3(nIn / 1024, 3), 256, 0, stream>>>(q, qb, k, kb, v, vb, nullptr, nullptr, nIn);
  cvt_f32_bf16<<<dim3(nW / 1024, 4), 256, 0, stream>>>(Wq, Wqb, Wk, Wkb, Wv, Wvb, Wo, Wob, nW);

  gemm_qkv<<<dim3(MTOT / 128, DIM / 128, 3), 256, 0, stream>>>(qb, kb, vb, Wqb, Wkb, Wvb,
                                                               gq, bq, gk, bk, qhb, khb, vTb);

  attn_kernel<<<dim3(512), 512, 0, stream>>>(qhb, khb, vTb, xb);

  gemm_out<<<dim3(MTOT / 128, DIM / 128), 256, 0, stream>>>(xb, Wob, bo, out);
}

// Round 10
// 133.635 us; speedup vs baseline: 2.4900x; 1.1656x over previous
//
#include <hip/hip_runtime.h>
#include <stdint.h>

// B=2, L=2048, DIM=1024, 16 heads x 64
#define BATCH 2
#define SEQ   2048
#define DIM   1024
#define NH    16
#define MTOT  (BATCH*SEQ)   // 4096
#define LN_EPS 1e-5f
// Q scale folded with -log2(e): sigmoid(s) = rcp(1 + exp2(s*-log2e))
#define Q_FOLD_SCALE (-0.1803368801111204f)   // 0.125 * -1.4426950408889634

typedef __bf16 bf16x8 __attribute__((ext_vector_type(8)));
typedef float  f32x4  __attribute__((ext_vector_type(4)));

__device__ __forceinline__ unsigned short f2bf(float f) {
  uint32_t u = __float_as_uint(f);
  u += 0x7fffu + ((u >> 16) & 1u);      // RNE
  return (unsigned short)(u >> 16);
}
__device__ __forceinline__ unsigned short f2bf_rh(float f) {  // round-half-up (P>=0)
  uint32_t u = __float_as_uint(f) + 0x8000u;
  return (unsigned short)(u >> 16);
}

__device__ __forceinline__ void gload_lds16(const void* g, void* lds) {
  __builtin_amdgcn_global_load_lds(
      (const __attribute__((address_space(1))) uint32_t*)g,
      (__attribute__((address_space(3))) uint32_t*)lds, 16, 0, 0);
}

#define VMCNT(n) asm volatile("s_waitcnt vmcnt(" #n ")" ::: "memory")
#define BAR() do { __builtin_amdgcn_s_barrier(); __builtin_amdgcn_sched_barrier(0); } while (0)
// Fence between LDS writes and subsequent LDS reads of the same buffer (TBAA-
// distinct types on Plds have no alias edge; block compile-time motion + wait).
#define DSFENCE() do {                                        \
    __builtin_amdgcn_sched_barrier(0);                        \
    asm volatile("s_waitcnt lgkmcnt(0)" ::: "memory");        \
    __builtin_amdgcn_sched_barrier(0);                        \
  } while (0)
#define ROT3(a, b, c) do { unsigned short* _tmp = (a); (a) = (b); (b) = (c); (c) = _tmp; } while (0)

// ---------------- f32 -> bf16 conversion ----------------
__global__ void cvt_f32_bf16(const float* __restrict__ s0, unsigned short* __restrict__ d0,
                             const float* __restrict__ s1, unsigned short* __restrict__ d1,
                             const float* __restrict__ s2, unsigned short* __restrict__ d2,
                             const float* __restrict__ s3, unsigned short* __restrict__ d3,
                             int n) {
  int z = blockIdx.y;
  const float* s = z == 0 ? s0 : z == 1 ? s1 : z == 2 ? s2 : s3;
  unsigned short* d = z == 0 ? d0 : z == 1 ? d1 : z == 2 ? d2 : d3;
  if (s == nullptr) return;
  int i = (blockIdx.x * 256 + threadIdx.x) * 4;
  if (i >= n) return;
  float4 v = *(const float4*)(s + i);
  ushort4 o;
  o.x = f2bf(v.x); o.y = f2bf(v.y); o.z = f2bf(v.z); o.w = f2bf(v.w);
  *(ushort4*)(d + i) = o;
}

// ---------------- fused QKV projections: depth-2 prefetch, 3 slots ----------
// Staging: 4 consecutive lanes read the 4 consecutive 16B chunks of one row's
// 64B K-slice (coalesced: 16 lines/inst vs 64 for lane=row). LDS row-major
// [128][32] bf16 with chunk slot c_lds = c_g ^ ((row>>1)&3); frag read XORs
// the same -> uniform 8-lane/4-bank-group = the b128 floor (same as before).
__global__ __launch_bounds__(256, 3)
void gemm_qkv(const unsigned short* __restrict__ Aq, const unsigned short* __restrict__ Ak,
              const unsigned short* __restrict__ Av,
              const unsigned short* __restrict__ Wqp, const unsigned short* __restrict__ Wkp,
              const unsigned short* __restrict__ Wvp,
              const float* __restrict__ gq, const float* __restrict__ bq,
              const float* __restrict__ gk, const float* __restrict__ bk,
              unsigned short* __restrict__ qh, unsigned short* __restrict__ kh,
              unsigned short* __restrict__ vT) {
  __shared__ unsigned short Asm[3][4096];  // [slot][row(128)][32] 8KB each
  __shared__ unsigned short Bsm[3][4096];
  const int z = blockIdx.z;
  const unsigned short* A = z == 0 ? Aq : z == 1 ? Ak : Av;
  const unsigned short* W = z == 0 ? Wqp : z == 1 ? Wkp : Wvp;
  const int t = threadIdx.x, w = t >> 6, l = t & 63, l15 = l & 15, lhi = l >> 4;
  const int wm = w >> 1, wn = w & 1;
  const int m0 = blockIdx.x * 128, n0 = blockIdx.y * 128;
  const int sr0 = t >> 2, sc = (t & 3) ^ (((t >> 2) >> 1) & 3);
  const int fsw = (l15 >> 1) & 3;          // frag-read XOR

  unsigned short *ac = &Asm[0][0], *an = &Asm[1][0], *af_ = &Asm[2][0];
  unsigned short *bc = &Bsm[0][0], *bn = &Bsm[1][0], *bf_ = &Bsm[2][0];

  f32x4 acc[4][4] = {};

#define STAGE_G(ap, bp, kt) do {                                                  \
    int k0 = (kt) * 32;                                                           \
    gload_lds16(A + (size_t)(m0 + sr0) * 1024 + k0 + sc * 8, (ap) + t * 8);       \
    gload_lds16(A + (size_t)(m0 + 64 + sr0) * 1024 + k0 + sc * 8,                 \
                (ap) + (t + 256) * 8);                                            \
    gload_lds16(W + (size_t)(n0 + sr0) * 1024 + k0 + sc * 8, (bp) + t * 8);       \
    gload_lds16(W + (size_t)(n0 + 64 + sr0) * 1024 + k0 + sc * 8,                 \
                (bp) + (t + 256) * 8);                                            \
  } while (0)

  STAGE_G(ac, bc, 0);
  STAGE_G(an, bn, 1);
  for (int kt = 0; kt < 32; ++kt) {
    if (kt < 30)       { STAGE_G(af_, bf_, kt + 2); VMCNT(8); }
    else if (kt == 30) { VMCNT(4); }
    else               { VMCNT(0); }
    BAR();                       // cur tile landed for ALL waves
    bf16x8 afr[4], bfr[4];
#pragma unroll
    for (int mi = 0; mi < 4; ++mi)
      afr[mi] = *(const bf16x8*)&ac[(wm * 64 + mi * 16 + l15) * 32 + ((lhi ^ fsw) * 8)];
#pragma unroll
    for (int ni = 0; ni < 4; ++ni)
      bfr[ni] = *(const bf16x8*)&bc[(wn * 64 + ni * 16 + l15) * 32 + ((lhi ^ fsw) * 8)];
    __builtin_amdgcn_s_setprio(1);
#pragma unroll
    for (int mi = 0; mi < 4; ++mi)
#pragma unroll
      for (int ni = 0; ni < 4; ++ni)
        acc[mi][ni] = __builtin_amdgcn_mfma_f32_16x16x32_bf16(afr[mi], bfr[ni], acc[mi][ni], 0, 0, 0);
    __builtin_amdgcn_s_setprio(0);
    BAR();                       // readers done before slot re-stage next step
    ROT3(ac, an, af_);
    ROT3(bc, bn, bf_);
  }
#undef STAGE_G

  const int h = (n0 >> 6) + wn;
  if (z == 2) {
#pragma unroll
    for (int mi = 0; mi < 4; ++mi)
#pragma unroll
      for (int r = 0; r < 4; ++r) {
        int gm = m0 + wm * 64 + mi * 16 + lhi * 4 + r;
        int b = gm >> 11, pos = gm & 2047;
#pragma unroll
        for (int ni = 0; ni < 4; ++ni)
          vT[(((size_t)(b * NH + h)) * 64 + ni * 16 + l15) * SEQ + pos] = f2bf(acc[mi][ni][r]);
      }
  } else {
    const float* G  = z ? gk : gq;
    const float* Bt = z ? bk : bq;
    unsigned short* outp = z ? kh : qh;
    const float scl = z ? 1.f : Q_FOLD_SCALE;
    float g[4], bt[4];
#pragma unroll
    for (int ni = 0; ni < 4; ++ni) { g[ni] = G[ni * 16 + l15]; bt[ni] = Bt[ni * 16 + l15]; }
#pragma unroll
    for (int mi = 0; mi < 4; ++mi)
#pragma unroll
      for (int r = 0; r < 4; ++r) {
        float x[4], s = 0.f, s2 = 0.f;
#pragma unroll
        for (int ni = 0; ni < 4; ++ni) { x[ni] = acc[mi][ni][r]; s += x[ni]; s2 += x[ni] * x[ni]; }
#pragma unroll
        for (int msk = 1; msk < 16; msk <<= 1) {
          s  += __shfl_xor(s,  msk, 64);
          s2 += __shfl_xor(s2, msk, 64);
        }
        float mu = s * (1.f / 64.f);
        float var = s2 * (1.f / 64.f) - mu * mu;
        float rstd = rsqrtf(var + LN_EPS);
        int gm = m0 + wm * 64 + mi * 16 + lhi * 4 + r;
        int b = gm >> 11, pos = gm & 2047;
        size_t base = (((size_t)(b * NH + h)) * SEQ + pos) * 64;
#pragma unroll
        for (int ni = 0; ni < 4; ++ni) {
          float y = ((x[ni] - mu) * rstd * g[ni] + bt[ni]) * scl;
          outp[base + ni * 16 + l15] = f2bf(y);
        }
      }
  }
}

// ---------------- out projection: out = x @ Wo^T + bo (f32), depth-2 ---------
__global__ __launch_bounds__(256, 3)
void gemm_out(const unsigned short* __restrict__ A, const unsigned short* __restrict__ W,
              const float* __restrict__ bias, float* __restrict__ outf) {
  __shared__ unsigned short Asm[3][4096];
  __shared__ unsigned short Bsm[3][4096];
  const int t = threadIdx.x, w = t >> 6, l = t & 63, l15 = l & 15, lhi = l >> 4;
  const int wm = w >> 1, wn = w & 1;
  const int m0 = blockIdx.x * 128, n0 = blockIdx.y * 128;
  const int sr0 = t >> 2, sc = (t & 3) ^ (((t >> 2) >> 1) & 3);
  const int fsw = (l15 >> 1) & 3;

  unsigned short *ac = &Asm[0][0], *an = &Asm[1][0], *af_ = &Asm[2][0];
  unsigned short *bc = &Bsm[0][0], *bn = &Bsm[1][0], *bf_ = &Bsm[2][0];
  f32x4 acc[4][4] = {};

#define STAGE_G(ap, bp, kt) do {                                                  \
    int k0 = (kt) * 32;                                                           \
    gload_lds16(A + (size_t)(m0 + sr0) * 1024 + k0 + sc * 8, (ap) + t * 8);       \
    gload_lds16(A + (size_t)(m0 + 64 + sr0) * 1024 + k0 + sc * 8,                 \
                (ap) + (t + 256) * 8);                                            \
    gload_lds16(W + (size_t)(n0 + sr0) * 1024 + k0 + sc * 8, (bp) + t * 8);       \
    gload_lds16(W + (size_t)(n0 + 64 + sr0) * 1024 + k0 + sc * 8,                 \
                (bp) + (t + 256) * 8);                                            \
  } while (0)

  STAGE_G(ac, bc, 0);
  STAGE_G(an, bn, 1);
  for (int kt = 0; kt < 32; ++kt) {
    if (kt < 30)       { STAGE_G(af_, bf_, kt + 2); VMCNT(8); }
    else if (kt == 30) { VMCNT(4); }
    else               { VMCNT(0); }
    BAR();
    bf16x8 afr[4], bfr[4];
#pragma unroll
    for (int mi = 0; mi < 4; ++mi)
      afr[mi] = *(const bf16x8*)&ac[(wm * 64 + mi * 16 + l15) * 32 + ((lhi ^ fsw) * 8)];
#pragma unroll
    for (int ni = 0; ni < 4; ++ni)
      bfr[ni] = *(const bf16x8*)&bc[(wn * 64 + ni * 16 + l15) * 32 + ((lhi ^ fsw) * 8)];
    __builtin_amdgcn_s_setprio(1);
#pragma unroll
    for (int mi = 0; mi < 4; ++mi)
#pragma unroll
      for (int ni = 0; ni < 4; ++ni)
        acc[mi][ni] = __builtin_amdgcn_mfma_f32_16x16x32_bf16(afr[mi], bfr[ni], acc[mi][ni], 0, 0, 0);
    __builtin_amdgcn_s_setprio(0);
    BAR();
    ROT3(ac, an, af_);
    ROT3(bc, bn, bf_);
  }
#undef STAGE_G
  float bb[4];
#pragma unroll
  for (int ni = 0; ni < 4; ++ni) bb[ni] = bias[n0 + wn * 64 + ni * 16 + l15];
#pragma unroll
  for (int mi = 0; mi < 4; ++mi)
#pragma unroll
    for (int r = 0; r < 4; ++r) {
      int gm = m0 + wm * 64 + mi * 16 + lhi * 4 + r;
      float* op = outf + (size_t)gm * 1024 + n0 + wn * 64 + l15;
#pragma unroll
      for (int ni = 0; ni < 4; ++ni) op[ni * 16] = acc[mi][ni][r] + bb[ni];
    }
}

// ---------------- Sigmoid attention: 8 waves x 16 q-rows (512 threads) -------
// (unchanged from R9 — staging already coalesced; pipeline proven)
__global__ __launch_bounds__(512, 4)
void attn_kernel(const unsigned short* __restrict__ qh,
                 const unsigned short* __restrict__ kh,
                 const unsigned short* __restrict__ vT,
                 unsigned short* __restrict__ x) {
  __shared__ unsigned short Klds[3][4096];      // [slot][kv_row][chunk^swz] 8KB
  __shared__ unsigned short Vlds[3][4096];      // [slot][d][chunk^swz]
  __shared__ unsigned short Plds[8 * 16 * 72];  // per-wave [16][72] (144B stride)
  const int t = threadIdx.x, w = t >> 6, l = t & 63, l15 = l & 15, lhi = l >> 4;
  const int L = blockIdx.x;
  const int xcd = L & 7, j = L >> 3;
  const int bh = xcd * 4 + (j >> 4);   // 4 heads per XCD
  const int qt = j & 15;
  const int b = bh >> 4;
  const unsigned short* Q = qh + (size_t)bh * SEQ * 64;
  const unsigned short* K = kh + (size_t)bh * SEQ * 64;
  const unsigned short* V = vT + (size_t)bh * 64 * SEQ;
  unsigned short* Pw = &Plds[w * 16 * 72];
  const int qbase = qt * 128 + w * 16;

  bf16x8 qf[2];
#pragma unroll
  for (int kb = 0; kb < 2; ++kb)
    qf[kb] = *(const bf16x8*)&Q[(size_t)(qbase + l15) * 64 + kb * 32 + lhi * 8];

  f32x4 o[4] = {};
  const int r0 = t >> 3, c0 = t & 7;   // t in [0,512): r0 covers 0..63

  unsigned short *kc = &Klds[0][0], *kn = &Klds[1][0], *kfu = &Klds[2][0];
  unsigned short *vc = &Vlds[0][0], *vn = &Vlds[1][0], *vfu = &Vlds[2][0];

#define STAGE_KV(kp, vp, kv0) do {                                                  \
    gload_lds16(K + (size_t)((kv0) + r0) * 64 + (c0 ^ (r0 & 7)) * 8, (kp) + t * 8); \
    gload_lds16(V + (size_t)r0 * SEQ + (kv0) + (c0 ^ (r0 & 7)) * 8, (vp) + t * 8);  \
  } while (0)

  STAGE_KV(kc, vc, 0);
  STAGE_KV(kn, vn, 64);
  for (int kv = 0; kv < 32; ++kv) {
    if (kv < 30)       { STAGE_KV(kfu, vfu, (kv + 2) * 64); VMCNT(4); }
    else if (kv == 30) { VMCNT(2); }
    else               { VMCNT(0); }
    BAR();                        // cur K/V tile valid for all waves

    // QK^T (Q pre-scaled by -0.125*log2e): s[ni], row=q(lhi*4+r), col=kv(ni*16+l15)
    f32x4 s[4] = {};
    __builtin_amdgcn_s_setprio(1);
#pragma unroll
    for (int ni = 0; ni < 4; ++ni)
#pragma unroll
      for (int kb = 0; kb < 2; ++kb) {
        bf16x8 kf = *(const bf16x8*)&kc[(ni * 16 + l15) * 64 + (((kb * 4 + lhi) ^ (l15 & 7)) * 8)];
        s[ni] = __builtin_amdgcn_mfma_f32_16x16x32_bf16(qf[kb], kf, s[ni], 0, 0, 0);
      }
    __builtin_amdgcn_s_setprio(0);

    // sigmoid = rcp(1 + exp2(s~)) -> bf16 -> per-wave LDS
#pragma unroll
    for (int ni = 0; ni < 4; ++ni)
#pragma unroll
      for (int r = 0; r < 4; ++r) {
        float p = __builtin_amdgcn_rcpf(1.0f + __builtin_amdgcn_exp2f(s[ni][r]));
        Pw[(lhi * 4 + r) * 72 + ni * 16 + l15] = f2bf_rh(p);
      }
    DSFENCE();                    // P writes complete before P reads

    // PV : O[16][64] += P[16][64] @ V[64][64]
    __builtin_amdgcn_s_setprio(1);
#pragma unroll
    for (int kq = 0; kq < 2; ++kq) {
      bf16x8 pf = *(const bf16x8*)&Pw[l15 * 72 + kq * 32 + lhi * 8];
#pragma unroll
      for (int di = 0; di < 4; ++di) {
        bf16x8 vf = *(const bf16x8*)&vc[(di * 16 + l15) * 64 + (((kq * 4 + lhi) ^ (l15 & 7)) * 8)];
        o[di] = __builtin_amdgcn_mfma_f32_16x16x32_bf16(pf, vf, o[di], 0, 0, 0);
      }
    }
    __builtin_amdgcn_s_setprio(0);
    BAR();                        // readers done before slot re-stage next step

    ROT3(kc, kn, kfu);
    ROT3(vc, vn, vfu);
  }
#undef STAGE_KV

#pragma unroll
  for (int r = 0; r < 4; ++r) {
    int pos = qbase + lhi * 4 + r;
    size_t base = ((size_t)b * SEQ + pos) * DIM + (bh & 15) * 64;
#pragma unroll
    for (int di = 0; di < 4; ++di)
      x[base + di * 16 + l15] = f2bf(o[di][r]);
  }
}

// ---------------- launch ----------------
extern "C" void kernel_launch(void* const* d_in, const int* in_sizes, int n_in,
                              void* d_out, int out_size, void* d_ws, size_t ws_size,
                              hipStream_t stream) {
  (void)in_sizes; (void)n_in; (void)out_size; (void)ws_size;
  const float* q  = (const float*)d_in[0];
  const float* k  = (const float*)d_in[1];
  const float* v  = (const float*)d_in[2];
  const float* Wq = (const float*)d_in[3];
  const float* Wk = (const float*)d_in[4];
  const float* Wv = (const float*)d_in[5];
  const float* gq = (const float*)d_in[6];
  const float* bq = (const float*)d_in[7];
  const float* gk = (const float*)d_in[8];
  const float* bk = (const float*)d_in[9];
  const float* Wo = (const float*)d_in[10];
  const float* bo = (const float*)d_in[11];
  float* out = (float*)d_out;

  char* ws = (char*)d_ws;
  const size_t MB = 1ull << 20;
  unsigned short* qb  = (unsigned short*)(ws + 0);        // 8MB, reused as x after attn
  unsigned short* kb  = (unsigned short*)(ws + 8  * MB);
  unsigned short* vb  = (unsigned short*)(ws + 16 * MB);
  unsigned short* Wqb = (unsigned short*)(ws + 24 * MB);
  unsigned short* Wkb = (unsigned short*)(ws + 26 * MB);
  unsigned short* Wvb = (unsigned short*)(ws + 28 * MB);
  unsigned short* Wob = (unsigned short*)(ws + 30 * MB);
  unsigned short* qhb = (unsigned short*)(ws + 32 * MB);  // [BH][L][64]
  unsigned short* khb = (unsigned short*)(ws + 40 * MB);  // [BH][L][64]
  unsigned short* vTb = (unsigned short*)(ws + 48 * MB);  // [BH][64][L]
  unsigned short* xb  = qb;

  const int nIn = MTOT * DIM;
  const int nW  = DIM * DIM;

  cvt_f32_bf16<<<dim3(nIn / 1024, 3), 256, 0, stream>>>(q, qb, k, kb, v, vb, nullptr, nullptr, nIn);
  cvt_f32_bf16<<<dim3(nW / 1024, 4), 256, 0, stream>>>(Wq, Wqb, Wk, Wkb, Wv, Wvb, Wo, Wob, nW);

  gemm_qkv<<<dim3(MTOT / 128, DIM / 128, 3), 256, 0, stream>>>(qb, kb, vb, Wqb, Wkb, Wvb,
                                                               gq, bq, gk, bk, qhb, khb, vTb);

  attn_kernel<<<dim3(512), 512, 0, stream>>>(qhb, khb, vTb, xb);

  gemm_out<<<dim3(MTOT / 128, DIM / 128), 256, 0, stream>>>(xb, Wob, bo, out);
}